// Round 1
// baseline (2826.002 us; speedup 1.0000x reference)
//
#include <hip/hip_runtime.h>
#include <hip/hip_bf16.h>
#include <cmath>

#define HW    32400
#define WIMG  180
#define DD    128
#define NHEADS 8
#define DHEAD 16
#define LTOK  225

// ---------------------------------------------------------------------------
// 1) 1x1 conv (channel projection) + BN + ReLU.  out[b,d,p], d0 block = 16 ch.
// ---------------------------------------------------------------------------
__global__ void __launch_bounds__(256) k_proj_bn_relu(
    const float* __restrict__ in, const float* __restrict__ w,
    const float* __restrict__ g, const float* __restrict__ be,
    const float* __restrict__ mu, const float* __restrict__ var,
    float* __restrict__ out, int C) {
  int p = blockIdx.x * 256 + threadIdx.x;
  if (p >= HW) return;
  int d0 = blockIdx.y * 16;
  int b  = blockIdx.z;
  const float* inp = in + (size_t)b * C * HW + p;
  float acc[16];
#pragma unroll
  for (int j = 0; j < 16; ++j) acc[j] = 0.f;
  for (int c = 0; c < C; ++c) {
    float x = inp[(size_t)c * HW];
#pragma unroll
    for (int j = 0; j < 16; ++j)
      acc[j] = fmaf(x, w[(d0 + j) * C + c], acc[j]);
  }
#pragma unroll
  for (int j = 0; j < 16; ++j) {
    int d = d0 + j;
    float s = g[d] * rsqrtf(var[d] + 1e-5f);
    float y = (acc[j] - mu[d]) * s + be[d];
    out[((size_t)b * DD + d) * HW + p] = fmaxf(y, 0.f);
  }
}

// ---------------------------------------------------------------------------
// 2) QKV projection: q from lid_p, k/v from cam_p.  Token layout
//    [bn][head][l][dh], one 16-wide d-group == one head slice.
// ---------------------------------------------------------------------------
__global__ void __launch_bounds__(256) k_qkv(
    const float* __restrict__ lid_p, const float* __restrict__ cam_p,
    const float* __restrict__ ipw, const float* __restrict__ ipb,
    float* __restrict__ q, float* __restrict__ k, float* __restrict__ v) {
  int p = blockIdx.x * 256 + threadIdx.x;
  if (p >= HW) return;
  int dg = blockIdx.y;           // 0..23
  int which = dg >> 3;           // 0=q, 1=k, 2=v
  int d0 = (dg & 7) * 16;
  int b  = blockIdx.z;
  const float* src = (which == 0 ? lid_p : cam_p) + (size_t)b * DD * HW + p;
  float acc[16];
#pragma unroll
  for (int j = 0; j < 16; ++j) acc[j] = ipb[which * DD + d0 + j];
  for (int c = 0; c < DD; ++c) {
    float x = src[(size_t)c * HW];
#pragma unroll
    for (int j = 0; j < 16; ++j)
      acc[j] = fmaf(x, ipw[(which * DD + d0 + j) * DD + c], acc[j]);
  }
  int hi = p / WIMG, wi = p % WIMG;
  int bn = b * 144 + (hi / 15) * 12 + (wi / 15);
  int l  = (hi % 15) * 15 + (wi % 15);
  int head = d0 >> 4;
  float* dst = (which == 0) ? q : (which == 1 ? k : v);
  size_t base = ((size_t)(bn * NHEADS + head) * LTOK + l) * DHEAD;
#pragma unroll
  for (int j = 0; j < 16; ++j) dst[base + j] = acc[j];
}

// ---------------------------------------------------------------------------
// 3) Attention per (bn, head). K,V staged in LDS; one thread per query row,
//    online softmax (broadcast LDS reads, no bank conflicts).
// ---------------------------------------------------------------------------
__global__ void __launch_bounds__(256) k_attn(
    const float* __restrict__ q, const float* __restrict__ k,
    const float* __restrict__ v, float* __restrict__ ctx) {
  __shared__ float ks[LTOK * DHEAD];
  __shared__ float vs[LTOK * DHEAD];
  int bn = blockIdx.x, h = blockIdx.y;
  size_t base = (size_t)(bn * NHEADS + h) * LTOK * DHEAD;
  const float* kp = k + base;
  const float* vp = v + base;
  for (int i = threadIdx.x; i < LTOK * DHEAD; i += 256) {
    ks[i] = kp[i];
    vs[i] = vp[i];
  }
  __syncthreads();
  int l = threadIdx.x;
  if (l >= LTOK) return;
  float qr[16];
  const float4* qv = (const float4*)(q + base + (size_t)l * DHEAD);
#pragma unroll
  for (int j = 0; j < 4; ++j) {
    float4 t = qv[j];
    qr[4 * j] = t.x; qr[4 * j + 1] = t.y; qr[4 * j + 2] = t.z; qr[4 * j + 3] = t.w;
  }
  float m = -1e30f, lsum = 0.f, o[16];
#pragma unroll
  for (int j = 0; j < 16; ++j) o[j] = 0.f;
  for (int kj = 0; kj < LTOK; ++kj) {
    float s = 0.f;
#pragma unroll
    for (int j = 0; j < 16; ++j) s = fmaf(qr[j], ks[kj * 16 + j], s);
    s *= 0.25f;  // 1/sqrt(16)
    float mn = fmaxf(m, s);
    float corr = __expf(m - mn);
    float pe   = __expf(s - mn);
    lsum = lsum * corr + pe;
#pragma unroll
    for (int j = 0; j < 16; ++j) o[j] = o[j] * corr + pe * vs[kj * 16 + j];
    m = mn;
  }
  float inv = 1.f / lsum;
  float* cp = ctx + ((size_t)bn * LTOK + l) * DD + h * DHEAD;
#pragma unroll
  for (int j = 0; j < 16; ++j) cp[j] = o[j] * inv;
}

// ---------------------------------------------------------------------------
// 4) out_proj + merge tokens + residual add (lid_p).  fused[b,d,p]
// ---------------------------------------------------------------------------
__global__ void __launch_bounds__(256) k_outproj(
    const float* __restrict__ ctx, const float* __restrict__ opw,
    const float* __restrict__ opb, const float* __restrict__ lid_p,
    float* __restrict__ fused) {
  int p = blockIdx.x * 256 + threadIdx.x;
  if (p >= HW) return;
  int d0 = blockIdx.y * 16;
  int b  = blockIdx.z;
  int hi = p / WIMG, wi = p % WIMG;
  int bn = b * 144 + (hi / 15) * 12 + (wi / 15);
  int l  = (hi % 15) * 15 + (wi % 15);
  const float* cr = ctx + ((size_t)bn * LTOK + l) * DD;
  float acc[16];
#pragma unroll
  for (int j = 0; j < 16; ++j) acc[j] = opb[d0 + j];
  for (int c = 0; c < DD; ++c) {
    float x = cr[c];
#pragma unroll
    for (int j = 0; j < 16; ++j)
      acc[j] = fmaf(x, opw[(d0 + j) * DD + c], acc[j]);
  }
#pragma unroll
  for (int j = 0; j < 16; ++j) {
    size_t oi = ((size_t)b * DD + d0 + j) * HW + p;
    fused[oi] = acc[j] + lid_p[oi];
  }
}

// ---------------------------------------------------------------------------
// 5) 3x3 conv (SAME) 128->256 + BN + ReLU.  15x15 tile, 8 oc / block,
//    16-ic input chunks staged in LDS (17x17 halo tile).
// ---------------------------------------------------------------------------
__global__ void __launch_bounds__(256) k_conv_bn_relu(
    const float* __restrict__ fused, const float* __restrict__ cw,
    const float* __restrict__ g, const float* __restrict__ be,
    const float* __restrict__ mu, const float* __restrict__ var,
    float* __restrict__ out) {
  __shared__ float tin[16 * 289];
  int tile = blockIdx.x;          // 0..143
  int ty = tile / 12, tx = tile % 12;
  int h0 = ty * 15, w0 = tx * 15;
  int oc0 = blockIdx.y * 8;
  int b   = blockIdx.z;
  int tid = threadIdx.x;
  int py = tid / 15, px = tid % 15;   // valid when tid < 225
  float acc[8];
#pragma unroll
  for (int j = 0; j < 8; ++j) acc[j] = 0.f;
  for (int icc = 0; icc < 8; ++icc) {
    __syncthreads();
    for (int i = tid; i < 16 * 289; i += 256) {
      int ch = i / 289, pp = i % 289;
      int ph = pp / 17 - 1 + h0, pw = pp % 17 - 1 + w0;
      float val = 0.f;
      if (ph >= 0 && ph < 180 && pw >= 0 && pw < 180)
        val = fused[((size_t)b * DD + icc * 16 + ch) * HW + ph * 180 + pw];
      tin[i] = val;
    }
    __syncthreads();
    if (tid < 225) {
      for (int ic = 0; ic < 16; ++ic) {
        int icg = icc * 16 + ic;
        float x[9];
        int bse = ic * 289 + py * 17 + px;
#pragma unroll
        for (int dy = 0; dy < 3; ++dy)
#pragma unroll
          for (int dx = 0; dx < 3; ++dx)
            x[dy * 3 + dx] = tin[bse + dy * 17 + dx];
#pragma unroll
        for (int oc = 0; oc < 8; ++oc) {
          const float* wr = cw + ((size_t)(oc0 + oc) * DD + icg) * 9;
          float a = acc[oc];
#pragma unroll
          for (int t = 0; t < 9; ++t) a = fmaf(x[t], wr[t], a);
          acc[oc] = a;
        }
      }
    }
  }
  if (tid < 225) {
#pragma unroll
    for (int oc = 0; oc < 8; ++oc) {
      int d = oc0 + oc;
      float s = g[d] * rsqrtf(var[d] + 1e-5f);
      float y = (acc[oc] - mu[d]) * s + be[d];
      out[((size_t)b * 256 + d) * HW + (h0 + py) * WIMG + (w0 + px)] =
          fmaxf(y, 0.f);
    }
  }
}

// ---------------------------------------------------------------------------
extern "C" void kernel_launch(void* const* d_in, const int* in_sizes, int n_in,
                              void* d_out, int out_size, void* d_ws, size_t ws_size,
                              hipStream_t stream) {
  const float* camera = (const float*)d_in[0];
  const float* lidar  = (const float*)d_in[1];
  const float* cam_w  = (const float*)d_in[2];
  const float* cam_g  = (const float*)d_in[3];
  const float* cam_b  = (const float*)d_in[4];
  const float* cam_m  = (const float*)d_in[5];
  const float* cam_v  = (const float*)d_in[6];
  const float* lid_w  = (const float*)d_in[7];
  const float* lid_g  = (const float*)d_in[8];
  const float* lid_b  = (const float*)d_in[9];
  const float* lid_m  = (const float*)d_in[10];
  const float* lid_v  = (const float*)d_in[11];
  const float* ipw    = (const float*)d_in[12];
  const float* ipb    = (const float*)d_in[13];
  const float* opw    = (const float*)d_in[14];
  const float* opb    = (const float*)d_in[15];
  const float* ocw    = (const float*)d_in[16];
  const float* ocg    = (const float*)d_in[17];
  const float* ocb    = (const float*)d_in[18];
  const float* ocm    = (const float*)d_in[19];
  const float* ocv    = (const float*)d_in[20];

  float* ws = (float*)d_ws;
  const size_t N1 = (size_t)2 * DD * HW;   // 8,294,400 floats = 33.2 MB
  float* cam_p = ws;
  float* lid_p = ws + N1;
  float* qb    = ws + 2 * N1;
  float* kb    = ws + 3 * N1;
  float* vb    = ws + 4 * N1;
  float* ctx   = ws + 5 * N1;
  float* fused = cam_p;   // cam_p dead after k_qkv

  dim3 blk(256);
  dim3 gproj(127, 8, 2);
  hipLaunchKernelGGL(k_proj_bn_relu, gproj, blk, 0, stream,
                     camera, cam_w, cam_g, cam_b, cam_m, cam_v, cam_p, 80);
  hipLaunchKernelGGL(k_proj_bn_relu, gproj, blk, 0, stream,
                     lidar, lid_w, lid_g, lid_b, lid_m, lid_v, lid_p, 256);
  dim3 gqkv(127, 24, 2);
  hipLaunchKernelGGL(k_qkv, gqkv, blk, 0, stream,
                     lid_p, cam_p, ipw, ipb, qb, kb, vb);
  dim3 gattn(288, 8);
  hipLaunchKernelGGL(k_attn, gattn, blk, 0, stream, qb, kb, vb, ctx);
  hipLaunchKernelGGL(k_outproj, gproj, blk, 0, stream,
                     ctx, opw, opb, lid_p, fused);
  dim3 gconv(144, 32, 2);
  hipLaunchKernelGGL(k_conv_bn_relu, gconv, blk, 0, stream,
                     fused, ocw, ocg, ocb, ocm, ocv, (float*)d_out);
}

// Round 2
// 1031.742 us; speedup vs baseline: 2.7391x; 2.7391x over previous
//
#include <hip/hip_runtime.h>
#include <hip/hip_bf16.h>
#include <cmath>

#define HW      32400
#define WIMG    180
#define DD      128
#define NHEADS  8
#define DHEAD   16
#define LTOK    225
#define PSTRIDE 64928            // 64800 + 128 slack rows per batch
#define FBROW   188
#define FBH     182
#define FBSZ    ((size_t)FBH * FBROW * 128)   // padded pixel-major conv input per batch

typedef __attribute__((ext_vector_type(8))) short bf16x8;
typedef __attribute__((ext_vector_type(4))) float f32x4;

__device__ __forceinline__ bf16x8 ldfrag(const __hip_bfloat16* p, int ld, int lane) {
  // fragment for mfma_f32_16x16x32_bf16: row = lane&15 (stride ld), k = (lane>>4)*8..+7 contiguous
  return *(const bf16x8*)(p + (size_t)(lane & 15) * ld + ((lane >> 4) << 3));
}

__device__ __forceinline__ float bf2f(unsigned int u) {
  return __uint_as_float(u << 16);
}

// ---------------------------------------------------------------------------
// weight prep: fp32 -> bf16 casts (and conv-weight transpose to [oc][tap][ic])
// ---------------------------------------------------------------------------
__global__ void k_cast(const float* __restrict__ in, __hip_bfloat16* __restrict__ out, int n) {
  int i = blockIdx.x * 256 + threadIdx.x;
  if (i < n) out[i] = __float2bfloat16(in[i]);
}

__global__ void k_prepw(const float* __restrict__ cw, __hip_bfloat16* __restrict__ wcb) {
  int i = blockIdx.x * 256 + threadIdx.x;
  if (i < 256 * 9 * 128) {
    int oc = i / 1152, t = (i % 1152) / 128, ic = i % 128;
    wcb[i] = __float2bfloat16(cw[(size_t)(oc * 128 + ic) * 9 + t]);
  }
}

__global__ void k_zero(uint4* __restrict__ p, int n16) {
  int i = blockIdx.x * 256 + threadIdx.x;
  if (i < n16) p[i] = make_uint4(0u, 0u, 0u, 0u);
}

// ---------------------------------------------------------------------------
// 1) 1x1 conv + BN + ReLU -> pixel-major bf16 [p][128]
// ---------------------------------------------------------------------------
__global__ void __launch_bounds__(256) k_proj_bn_relu(
    const float* __restrict__ in, const float* __restrict__ w,
    const float* __restrict__ g, const float* __restrict__ be,
    const float* __restrict__ mu, const float* __restrict__ var,
    __hip_bfloat16* __restrict__ outp, int C) {
  int p = blockIdx.x * 256 + threadIdx.x;
  if (p >= HW) return;
  int d0 = blockIdx.y * 16;
  int b  = blockIdx.z;
  const float* inp = in + (size_t)b * C * HW + p;
  float acc[16];
#pragma unroll
  for (int j = 0; j < 16; ++j) acc[j] = 0.f;
  for (int c = 0; c < C; ++c) {
    float x = inp[(size_t)c * HW];
#pragma unroll
    for (int j = 0; j < 16; ++j)
      acc[j] = fmaf(x, w[(d0 + j) * C + c], acc[j]);
  }
  __hip_bfloat16 tmp[16];
#pragma unroll
  for (int j = 0; j < 16; ++j) {
    int d = d0 + j;
    float s = g[d] * rsqrtf(var[d] + 1e-5f);
    float y = (acc[j] - mu[d]) * s + be[d];
    tmp[j] = __float2bfloat16(fmaxf(y, 0.f));
  }
  uint4* dst = (uint4*)(outp + ((size_t)b * PSTRIDE + p) * 128 + d0);
  dst[0] = ((uint4*)tmp)[0];
  dst[1] = ((uint4*)tmp)[1];
}

// ---------------------------------------------------------------------------
// 2) MFMA GEMM: out[m][n] = sum_k A[m][k]*B[n][k] + bias[n]   (bf16 in/out)
//    block 128x128, 4 waves of 64x64. Direct-from-L2, no LDS.
// ---------------------------------------------------------------------------
__global__ void __launch_bounds__(256) k_gemm_bias(
    const __hip_bfloat16* __restrict__ A, const __hip_bfloat16* __restrict__ B,
    const float* __restrict__ bias, __hip_bfloat16* __restrict__ out,
    int K, int ldout) {
  int m0 = blockIdx.x * 128, n0 = blockIdx.y * 128, b = blockIdx.z;
  int lane = threadIdx.x & 63, wid = threadIdx.x >> 6;
  int wm = (wid >> 1) * 64, wn = (wid & 1) * 64;
  const __hip_bfloat16* Ab = A + (size_t)b * PSTRIDE * K;
  f32x4 acc[4][4] = {};
  for (int kc = 0; kc < K; kc += 32) {
    bf16x8 af[4], bfr[4];
#pragma unroll
    for (int i = 0; i < 4; ++i)
      af[i] = ldfrag(Ab + (size_t)(m0 + wm + i * 16) * K + kc, K, lane);
#pragma unroll
    for (int j = 0; j < 4; ++j)
      bfr[j] = ldfrag(B + (size_t)(n0 + wn + j * 16) * K + kc, K, lane);
#pragma unroll
    for (int i = 0; i < 4; ++i)
#pragma unroll
      for (int j = 0; j < 4; ++j)
        acc[i][j] = __builtin_amdgcn_mfma_f32_16x16x32_bf16(af[i], bfr[j], acc[i][j], 0, 0, 0);
  }
  int col = lane & 15, rq = lane >> 4;
  __hip_bfloat16* ob = out + (size_t)b * PSTRIDE * ldout;
#pragma unroll
  for (int j = 0; j < 4; ++j) {
    int n = n0 + wn + j * 16 + col;
    float bs = bias[n];
#pragma unroll
    for (int i = 0; i < 4; ++i) {
#pragma unroll
      for (int r = 0; r < 4; ++r) {
        int m = m0 + wm + i * 16 + rq * 4 + r;
        if (m < HW) ob[(size_t)m * ldout + n] = __float2bfloat16(acc[i][j][r] + bs);
      }
    }
  }
}

// ---------------------------------------------------------------------------
// 3) attention per (bn, head): gather K/V rows into LDS (fp32), per-thread
//    online softmax over 225 keys. q read / ctx written in-place (same buffer).
// ---------------------------------------------------------------------------
__global__ void __launch_bounds__(256) k_attn(
    const __hip_bfloat16* __restrict__ qc, const __hip_bfloat16* __restrict__ kvb,
    __hip_bfloat16* __restrict__ ctx) {
  __shared__ float ks[LTOK * 16];
  __shared__ float vs[LTOK * 16];
  int bn = blockIdx.x, hh = blockIdx.y;
  int b = bn / 144, rr = bn % 144, tby = rr / 12, tbx = rr % 12;
  int tid = threadIdx.x;
  int p = 0;
  if (tid < LTOK) {
    p = (tby * 15 + tid / 15) * WIMG + tbx * 15 + tid % 15;
    const uint4* kp = (const uint4*)(kvb + ((size_t)b * PSTRIDE + p) * 256 + hh * 16);
    uint4 k0 = kp[0], k1 = kp[1];      // 16 bf16 of K
    uint4 v0 = kp[16], v1 = kp[17];    // +128 elements = 8 uint4
    float* kd = &ks[tid * 16];
    float* vd = &vs[tid * 16];
    unsigned int kw[8] = {k0.x, k0.y, k0.z, k0.w, k1.x, k1.y, k1.z, k1.w};
    unsigned int vw[8] = {v0.x, v0.y, v0.z, v0.w, v1.x, v1.y, v1.z, v1.w};
#pragma unroll
    for (int j = 0; j < 8; ++j) {
      kd[2 * j]     = bf2f(kw[j] & 0xffffu);
      kd[2 * j + 1] = bf2f(kw[j] >> 16);
      vd[2 * j]     = bf2f(vw[j] & 0xffffu);
      vd[2 * j + 1] = bf2f(vw[j] >> 16);
    }
  }
  __syncthreads();
  if (tid >= LTOK) return;
  float qr[16];
  {
    const uint4* qp = (const uint4*)(qc + ((size_t)b * PSTRIDE + p) * 128 + hh * 16);
    uint4 q0 = qp[0], q1 = qp[1];
    unsigned int qw[8] = {q0.x, q0.y, q0.z, q0.w, q1.x, q1.y, q1.z, q1.w};
#pragma unroll
    for (int j = 0; j < 8; ++j) {
      qr[2 * j]     = bf2f(qw[j] & 0xffffu);
      qr[2 * j + 1] = bf2f(qw[j] >> 16);
    }
  }
  float m = -1e30f, lsum = 0.f, o[16];
#pragma unroll
  for (int j = 0; j < 16; ++j) o[j] = 0.f;
  for (int kj = 0; kj < LTOK; ++kj) {
    float s = 0.f;
#pragma unroll
    for (int j = 0; j < 16; ++j) s = fmaf(qr[j], ks[kj * 16 + j], s);
    s *= 0.25f;
    float mn = fmaxf(m, s);
    float corr = __expf(m - mn);
    float pe   = __expf(s - mn);
    lsum = lsum * corr + pe;
#pragma unroll
    for (int j = 0; j < 16; ++j) o[j] = o[j] * corr + pe * vs[kj * 16 + j];
    m = mn;
  }
  float inv = 1.f / lsum;
  __hip_bfloat16 tmp[16];
#pragma unroll
  for (int j = 0; j < 16; ++j) tmp[j] = __float2bfloat16(o[j] * inv);
  uint4* dst = (uint4*)(ctx + ((size_t)b * PSTRIDE + p) * 128 + hh * 16);
  dst[0] = ((uint4*)tmp)[0];
  dst[1] = ((uint4*)tmp)[1];
}

// ---------------------------------------------------------------------------
// 4) out-proj MFMA GEMM (K=N=128) + bias + residual(lid_bf) -> padded fb bf16
// ---------------------------------------------------------------------------
__global__ void __launch_bounds__(256) k_outproj_mfma(
    const __hip_bfloat16* __restrict__ ctx, const __hip_bfloat16* __restrict__ wob,
    const float* __restrict__ opb, const __hip_bfloat16* __restrict__ lidb,
    __hip_bfloat16* __restrict__ fb) {
  int m0 = blockIdx.x * 128, b = blockIdx.z;
  int lane = threadIdx.x & 63, wid = threadIdx.x >> 6;
  int wm = (wid >> 1) * 64, wn = (wid & 1) * 64;
  const __hip_bfloat16* Ab = ctx + (size_t)b * PSTRIDE * 128;
  f32x4 acc[4][4] = {};
  for (int kc = 0; kc < 128; kc += 32) {
    bf16x8 af[4], bfr[4];
#pragma unroll
    for (int i = 0; i < 4; ++i)
      af[i] = ldfrag(Ab + (size_t)(m0 + wm + i * 16) * 128 + kc, 128, lane);
#pragma unroll
    for (int j = 0; j < 4; ++j)
      bfr[j] = ldfrag(wob + (size_t)(wn + j * 16) * 128 + kc, 128, lane);
#pragma unroll
    for (int i = 0; i < 4; ++i)
#pragma unroll
      for (int j = 0; j < 4; ++j)
        acc[i][j] = __builtin_amdgcn_mfma_f32_16x16x32_bf16(af[i], bfr[j], acc[i][j], 0, 0, 0);
  }
  int col = lane & 15, rq = lane >> 4;
  const __hip_bfloat16* lb = lidb + (size_t)b * PSTRIDE * 128;
  __hip_bfloat16* fbp = fb + (size_t)b * FBSZ;
#pragma unroll
  for (int j = 0; j < 4; ++j) {
    int n = wn + j * 16 + col;
    float bs = opb[n];
#pragma unroll
    for (int i = 0; i < 4; ++i) {
#pragma unroll
      for (int r = 0; r < 4; ++r) {
        int m = m0 + wm + i * 16 + rq * 4 + r;
        if (m < HW) {
          float v = acc[i][j][r] + bs + __bfloat162float(lb[(size_t)m * 128 + n]);
          int hh = m / WIMG, ww = m % WIMG;
          fbp[((size_t)(hh + 1) * FBROW + (ww + 1)) * 128 + n] = __float2bfloat16(v);
        }
      }
    }
  }
}

// ---------------------------------------------------------------------------
// 5) 3x3 conv 128->256 + BN + ReLU, implicit MFMA GEMM.
//    block = 60(+4 pad) pixels of one image row x 256 oc; 4 waves (64 oc each).
// ---------------------------------------------------------------------------
__global__ void __launch_bounds__(256) k_conv_mfma(
    const __hip_bfloat16* __restrict__ fb, const __hip_bfloat16* __restrict__ wcb,
    const float* __restrict__ g, const float* __restrict__ be,
    const float* __restrict__ mu, const float* __restrict__ var,
    float* __restrict__ out) {
  int bx = blockIdx.x;
  int h = bx / 3, w0 = (bx % 3) * 60;
  int b = blockIdx.z;
  int lane = threadIdx.x & 63, wid = threadIdx.x >> 6;
  int nb = wid * 64;
  const __hip_bfloat16* fbb = fb + (size_t)b * FBSZ;
  f32x4 acc[4][4] = {};
  for (int chunk = 0; chunk < 4; ++chunk) {
    int kof = chunk * 32;
    for (int dy = 0; dy < 3; ++dy) {
      const __hip_bfloat16* arow = fbb + (size_t)(h + dy) * FBROW * 128 + kof;
#pragma unroll
      for (int dx = 0; dx < 3; ++dx) {
        const __hip_bfloat16* abase = arow + (size_t)(w0 + dx) * 128;
        const __hip_bfloat16* bbase = wcb + (size_t)nb * 1152 + (dy * 3 + dx) * 128 + kof;
        bf16x8 af[4], bfr[4];
#pragma unroll
        for (int i = 0; i < 4; ++i) af[i] = ldfrag(abase + (size_t)i * 16 * 128, 128, lane);
#pragma unroll
        for (int j = 0; j < 4; ++j) bfr[j] = ldfrag(bbase + (size_t)j * 16 * 1152, 1152, lane);
#pragma unroll
        for (int i = 0; i < 4; ++i)
#pragma unroll
          for (int j = 0; j < 4; ++j)
            acc[i][j] = __builtin_amdgcn_mfma_f32_16x16x32_bf16(af[i], bfr[j], acc[i][j], 0, 0, 0);
      }
    }
  }
  int col = lane & 15, rq = lane >> 4;
#pragma unroll
  for (int j = 0; j < 4; ++j) {
    int oc = nb + j * 16 + col;
    float s = g[oc] * rsqrtf(var[oc] + 1e-5f);
    float mm = mu[oc], bb = be[oc];
#pragma unroll
    for (int i = 0; i < 4; ++i) {
      int mbase = i * 16 + rq * 4;
      if (mbase < 60) {
        float4 o4;
        o4.x = fmaxf((acc[i][j][0] - mm) * s + bb, 0.f);
        o4.y = fmaxf((acc[i][j][1] - mm) * s + bb, 0.f);
        o4.z = fmaxf((acc[i][j][2] - mm) * s + bb, 0.f);
        o4.w = fmaxf((acc[i][j][3] - mm) * s + bb, 0.f);
        *(float4*)(&out[(size_t)(b * 256 + oc) * HW + h * WIMG + w0 + mbase]) = o4;
      }
    }
  }
}

// ---------------------------------------------------------------------------
extern "C" void kernel_launch(void* const* d_in, const int* in_sizes, int n_in,
                              void* d_out, int out_size, void* d_ws, size_t ws_size,
                              hipStream_t stream) {
  const float* camera = (const float*)d_in[0];
  const float* lidar  = (const float*)d_in[1];
  const float* cam_w  = (const float*)d_in[2];
  const float* cam_g  = (const float*)d_in[3];
  const float* cam_b  = (const float*)d_in[4];
  const float* cam_m  = (const float*)d_in[5];
  const float* cam_v  = (const float*)d_in[6];
  const float* lid_w  = (const float*)d_in[7];
  const float* lid_g  = (const float*)d_in[8];
  const float* lid_b  = (const float*)d_in[9];
  const float* lid_m  = (const float*)d_in[10];
  const float* lid_v  = (const float*)d_in[11];
  const float* ipw    = (const float*)d_in[12];
  const float* ipb    = (const float*)d_in[13];
  const float* opw    = (const float*)d_in[14];
  const float* opb    = (const float*)d_in[15];
  const float* ocw    = (const float*)d_in[16];
  const float* ocg    = (const float*)d_in[17];
  const float* ocb    = (const float*)d_in[18];
  const float* ocm    = (const float*)d_in[19];
  const float* ocv    = (const float*)d_in[20];

  __hip_bfloat16* ws = (__hip_bfloat16*)d_ws;
  const size_t NP = (size_t)2 * PSTRIDE * 128;   // 16,621,568 elements
  __hip_bfloat16* cam_bf = ws;                    // aliased by fb later
  __hip_bfloat16* lid_bf = ws + NP;
  __hip_bfloat16* qc     = ws + 2 * NP;           // q, then ctx (in-place)
  __hip_bfloat16* kvb    = ws + 3 * NP;           // [p][256], 2*NP elements
  __hip_bfloat16* wipb   = ws + 5 * NP;           // 384*128
  __hip_bfloat16* wob    = wipb + 384 * 128;      // 128*128
  __hip_bfloat16* wcb    = wob + 128 * 128;       // 256*9*128
  __hip_bfloat16* fbbuf  = cam_bf;                // 2*FBSZ elements (fits in NP)

  dim3 blk(256);
  // weight prep
  hipLaunchKernelGGL(k_cast, dim3(192), blk, 0, stream, ipw, wipb, 384 * 128);
  hipLaunchKernelGGL(k_cast, dim3(64), blk, 0, stream, opw, wob, 128 * 128);
  hipLaunchKernelGGL(k_prepw, dim3(1152), blk, 0, stream, ocw, wcb);
  // projections -> pixel-major bf16
  dim3 gproj(127, 8, 2);
  hipLaunchKernelGGL(k_proj_bn_relu, gproj, blk, 0, stream,
                     camera, cam_w, cam_g, cam_b, cam_m, cam_v, cam_bf, 80);
  hipLaunchKernelGGL(k_proj_bn_relu, gproj, blk, 0, stream,
                     lidar, lid_w, lid_g, lid_b, lid_m, lid_v, lid_bf, 256);
  // qkv GEMMs
  hipLaunchKernelGGL(k_gemm_bias, dim3(507, 1, 2), blk, 0, stream,
                     lid_bf, wipb, ipb, qc, 128, 128);
  hipLaunchKernelGGL(k_gemm_bias, dim3(507, 2, 2), blk, 0, stream,
                     cam_bf, wipb + 128 * 128, ipb + 128, kvb, 128, 256);
  // attention (qc -> qc)
  hipLaunchKernelGGL(k_attn, dim3(288, 8), blk, 0, stream, qc, kvb, qc);
  // zero padded fb (aliases cam_bf, which is dead now)
  int n16 = (int)((2 * FBSZ * 2) / 16);
  hipLaunchKernelGGL(k_zero, dim3((n16 + 255) / 256), blk, 0, stream, (uint4*)fbbuf, n16);
  // out-proj + residual -> fb
  hipLaunchKernelGGL(k_outproj_mfma, dim3(507, 1, 2), blk, 0, stream,
                     qc, wob, opb, lid_bf, fbbuf);
  // conv + BN + ReLU
  hipLaunchKernelGGL(k_conv_mfma, dim3(540, 1, 2), blk, 0, stream,
                     fbbuf, wcb, ocg, ocb, ocm, ocv, (float*)d_out);
}

// Round 3
// 502.002 us; speedup vs baseline: 5.6295x; 2.0553x over previous
//
#include <hip/hip_runtime.h>
#include <hip/hip_bf16.h>
#include <cmath>

#define HW      32400
#define WIMG    180
#define DD      128
#define NHEADS  8
#define DHEAD   16
#define LTOK    225
#define PSTRIDE 64928            // 32400 + slack per batch (kept from r2 layout)
#define FBROW   188
#define FBH     182
#define FBSZ    ((size_t)FBH * FBROW * 128)   // padded pixel-major conv input per batch

typedef __attribute__((ext_vector_type(8))) short bf16x8;
typedef __attribute__((ext_vector_type(4))) float f32x4;

__device__ __forceinline__ bf16x8 ldfrag(const __hip_bfloat16* p, int ld, int lane) {
  // fragment for mfma_f32_16x16x32_bf16: row = lane&15 (stride ld), k = (lane>>4)*8..+7 contiguous
  return *(const bf16x8*)(p + (size_t)(lane & 15) * ld + ((lane >> 4) << 3));
}

__device__ __forceinline__ float bf2f(unsigned int u) {
  return __uint_as_float(u << 16);
}

__device__ __forceinline__ unsigned short f2bf(float x) {
  unsigned int b = __float_as_uint(x);
  return (unsigned short)((b + 0x7fffu + ((b >> 16) & 1u)) >> 16);
}

// ---------------------------------------------------------------------------
// weight prep
// ---------------------------------------------------------------------------
__global__ void k_cast(const float* __restrict__ in, __hip_bfloat16* __restrict__ out, int n) {
  int i = blockIdx.x * 256 + threadIdx.x;
  if (i < n) out[i] = __float2bfloat16(in[i]);
}

// proj weights: [128][C] fp32 -> [128][Kpad] bf16, zero-padded in k
__global__ void k_prepproj(const float* __restrict__ w, __hip_bfloat16* __restrict__ wb,
                           int C, int Kpad) {
  int i = blockIdx.x * 256 + threadIdx.x;
  if (i >= 128 * Kpad) return;
  int d = i / Kpad, c = i % Kpad;
  wb[i] = (c < C) ? __float2bfloat16(w[d * C + c]) : __float2bfloat16(0.f);
}

__global__ void k_prepw(const float* __restrict__ cw, __hip_bfloat16* __restrict__ wcb) {
  int i = blockIdx.x * 256 + threadIdx.x;
  if (i < 256 * 9 * 128) {
    int oc = i / 1152, t = (i % 1152) / 128, ic = i % 128;
    wcb[i] = __float2bfloat16(cw[(size_t)(oc * 128 + ic) * 9 + t]);
  }
}

__global__ void k_zero(uint4* __restrict__ p, int n16) {
  int i = blockIdx.x * 256 + threadIdx.x;
  if (i < n16) p[i] = make_uint4(0u, 0u, 0u, 0u);
}

// ---------------------------------------------------------------------------
// 1) 1x1 conv + BN + ReLU as implicit MFMA GEMM.
//    A = input [C][HW] transposed to LDS bf16 [128p][64c] (XOR-swizzled),
//    B = pre-cast weights [128d][Kpad].  Out: pixel-major bf16 [p][128].
// ---------------------------------------------------------------------------
__global__ void __launch_bounds__(256) k_proj_mfma(
    const float* __restrict__ in, const __hip_bfloat16* __restrict__ wb,
    const float* __restrict__ g, const float* __restrict__ be,
    const float* __restrict__ mu, const float* __restrict__ var,
    __hip_bfloat16* __restrict__ outp, int C, int Kpad) {
  __shared__ __hip_bfloat16 sa[128 * 64];
  int m0 = blockIdx.x * 128;
  int b = blockIdx.z;
  int tid = threadIdx.x, lane = tid & 63, wid = tid >> 6;
  int wm = (wid >> 1) * 64, wn = (wid & 1) * 64;
  const float* inb = in + (size_t)b * C * HW;
  int sp = (tid >> 1) & 127;        // staging pixel row (each row by 2 threads)
  int sc4 = (tid & 1) * 4;          // odd/even c interleave (spreads LDS banks)
  int gp = m0 + sp;
  bool pok = gp < HW;
  f32x4 acc[4][4] = {};
  for (int kc = 0; kc < Kpad; kc += 64) {
    __syncthreads();
#pragma unroll
    for (int it = 0; it < 8; ++it) {
      int lc = sc4 + it * 8;        // 0..63, multiples of 4
      int c = kc + lc;
      unsigned short u[4];
#pragma unroll
      for (int j = 0; j < 4; ++j) {
        float x = (pok && (c + j) < C) ? inb[(size_t)(c + j) * HW + gp] : 0.f;
        u[j] = f2bf(x);
      }
      int blk = (lc >> 3) ^ (sp & 7);
      char* dst = (char*)sa + sp * 128 + blk * 16 + (lc & 7) * 2;
      *(uint2*)dst = make_uint2(((unsigned)u[1] << 16) | u[0],
                                ((unsigned)u[3] << 16) | u[2]);
    }
    __syncthreads();
#pragma unroll
    for (int ks = 0; ks < 2; ++ks) {
      bf16x8 af[4], bfr[4];
#pragma unroll
      for (int i = 0; i < 4; ++i) {
        int pr = wm + i * 16 + (lane & 15);
        int blk = ((ks * 4 + (lane >> 4)) ^ (pr & 7));
        af[i] = *(const bf16x8*)((const char*)sa + pr * 128 + blk * 16);
      }
#pragma unroll
      for (int j = 0; j < 4; ++j)
        bfr[j] = ldfrag(wb + (size_t)(wn + j * 16) * Kpad + kc + ks * 32, Kpad, lane);
#pragma unroll
      for (int i = 0; i < 4; ++i)
#pragma unroll
        for (int j = 0; j < 4; ++j)
          acc[i][j] = __builtin_amdgcn_mfma_f32_16x16x32_bf16(af[i], bfr[j], acc[i][j], 0, 0, 0);
    }
  }
  int col = lane & 15, rq = lane >> 4;
  __hip_bfloat16* ob = outp + (size_t)b * PSTRIDE * 128;
#pragma unroll
  for (int j = 0; j < 4; ++j) {
    int d = wn + j * 16 + col;
    float s = g[d] * rsqrtf(var[d] + 1e-5f);
    float mm = mu[d], bb = be[d];
#pragma unroll
    for (int i = 0; i < 4; ++i) {
#pragma unroll
      for (int r = 0; r < 4; ++r) {
        int m = m0 + wm + i * 16 + rq * 4 + r;
        if (m < HW) {
          float y = (acc[i][j][r] - mm) * s + bb;
          ob[(size_t)m * 128 + d] = __float2bfloat16(fmaxf(y, 0.f));
        }
      }
    }
  }
}

// ---------------------------------------------------------------------------
// 2) MFMA GEMM: out[m][n] = sum_k A[m][k]*B[n][k] + bias[n]   (bf16 in/out)
// ---------------------------------------------------------------------------
__global__ void __launch_bounds__(256) k_gemm_bias(
    const __hip_bfloat16* __restrict__ A, const __hip_bfloat16* __restrict__ B,
    const float* __restrict__ bias, __hip_bfloat16* __restrict__ out,
    int K, int ldout) {
  int m0 = blockIdx.x * 128, n0 = blockIdx.y * 128, b = blockIdx.z;
  int lane = threadIdx.x & 63, wid = threadIdx.x >> 6;
  int wm = (wid >> 1) * 64, wn = (wid & 1) * 64;
  const __hip_bfloat16* Ab = A + (size_t)b * PSTRIDE * K;
  f32x4 acc[4][4] = {};
  for (int kc = 0; kc < K; kc += 32) {
    bf16x8 af[4], bfr[4];
#pragma unroll
    for (int i = 0; i < 4; ++i)
      af[i] = ldfrag(Ab + (size_t)(m0 + wm + i * 16) * K + kc, K, lane);
#pragma unroll
    for (int j = 0; j < 4; ++j)
      bfr[j] = ldfrag(B + (size_t)(n0 + wn + j * 16) * K + kc, K, lane);
#pragma unroll
    for (int i = 0; i < 4; ++i)
#pragma unroll
      for (int j = 0; j < 4; ++j)
        acc[i][j] = __builtin_amdgcn_mfma_f32_16x16x32_bf16(af[i], bfr[j], acc[i][j], 0, 0, 0);
  }
  int col = lane & 15, rq = lane >> 4;
  __hip_bfloat16* ob = out + (size_t)b * PSTRIDE * ldout;
#pragma unroll
  for (int j = 0; j < 4; ++j) {
    int n = n0 + wn + j * 16 + col;
    float bs = bias[n];
#pragma unroll
    for (int i = 0; i < 4; ++i) {
#pragma unroll
      for (int r = 0; r < 4; ++r) {
        int m = m0 + wm + i * 16 + rq * 4 + r;
        if (m < HW) ob[(size_t)m * ldout + n] = __float2bfloat16(acc[i][j][r] + bs);
      }
    }
  }
}

// ---------------------------------------------------------------------------
// 3) attention per (bn, head)
// ---------------------------------------------------------------------------
__global__ void __launch_bounds__(256) k_attn(
    const __hip_bfloat16* __restrict__ qc, const __hip_bfloat16* __restrict__ kvb,
    __hip_bfloat16* __restrict__ ctx) {
  __shared__ float ks[LTOK * 16];
  __shared__ float vs[LTOK * 16];
  int bn = blockIdx.x, hh = blockIdx.y;
  int b = bn / 144, rr = bn % 144, tby = rr / 12, tbx = rr % 12;
  int tid = threadIdx.x;
  int p = 0;
  if (tid < LTOK) {
    p = (tby * 15 + tid / 15) * WIMG + tbx * 15 + tid % 15;
    const uint4* kp = (const uint4*)(kvb + ((size_t)b * PSTRIDE + p) * 256 + hh * 16);
    uint4 k0 = kp[0], k1 = kp[1];
    uint4 v0 = kp[16], v1 = kp[17];
    float* kd = &ks[tid * 16];
    float* vd = &vs[tid * 16];
    unsigned int kw[8] = {k0.x, k0.y, k0.z, k0.w, k1.x, k1.y, k1.z, k1.w};
    unsigned int vw[8] = {v0.x, v0.y, v0.z, v0.w, v1.x, v1.y, v1.z, v1.w};
#pragma unroll
    for (int j = 0; j < 8; ++j) {
      kd[2 * j]     = bf2f(kw[j] & 0xffffu);
      kd[2 * j + 1] = bf2f(kw[j] >> 16);
      vd[2 * j]     = bf2f(vw[j] & 0xffffu);
      vd[2 * j + 1] = bf2f(vw[j] >> 16);
    }
  }
  __syncthreads();
  if (tid >= LTOK) return;
  float qr[16];
  {
    const uint4* qp = (const uint4*)(qc + ((size_t)b * PSTRIDE + p) * 128 + hh * 16);
    uint4 q0 = qp[0], q1 = qp[1];
    unsigned int qw[8] = {q0.x, q0.y, q0.z, q0.w, q1.x, q1.y, q1.z, q1.w};
#pragma unroll
    for (int j = 0; j < 8; ++j) {
      qr[2 * j]     = bf2f(qw[j] & 0xffffu);
      qr[2 * j + 1] = bf2f(qw[j] >> 16);
    }
  }
  float m = -1e30f, lsum = 0.f, o[16];
#pragma unroll
  for (int j = 0; j < 16; ++j) o[j] = 0.f;
  for (int kj = 0; kj < LTOK; ++kj) {
    float s = 0.f;
#pragma unroll
    for (int j = 0; j < 16; ++j) s = fmaf(qr[j], ks[kj * 16 + j], s);
    s *= 0.25f;
    float mn = fmaxf(m, s);
    float corr = __expf(m - mn);
    float pe   = __expf(s - mn);
    lsum = lsum * corr + pe;
#pragma unroll
    for (int j = 0; j < 16; ++j) o[j] = o[j] * corr + pe * vs[kj * 16 + j];
    m = mn;
  }
  float inv = 1.f / lsum;
  __hip_bfloat16 tmp[16];
#pragma unroll
  for (int j = 0; j < 16; ++j) tmp[j] = __float2bfloat16(o[j] * inv);
  uint4* dst = (uint4*)(ctx + ((size_t)b * PSTRIDE + p) * 128 + hh * 16);
  dst[0] = ((uint4*)tmp)[0];
  dst[1] = ((uint4*)tmp)[1];
}

// ---------------------------------------------------------------------------
// 4) out-proj MFMA GEMM (K=N=128) + bias + residual(lid_bf) -> padded fb bf16
// ---------------------------------------------------------------------------
__global__ void __launch_bounds__(256) k_outproj_mfma(
    const __hip_bfloat16* __restrict__ ctx, const __hip_bfloat16* __restrict__ wob,
    const float* __restrict__ opb, const __hip_bfloat16* __restrict__ lidb,
    __hip_bfloat16* __restrict__ fb) {
  int m0 = blockIdx.x * 128, b = blockIdx.z;
  int lane = threadIdx.x & 63, wid = threadIdx.x >> 6;
  int wm = (wid >> 1) * 64, wn = (wid & 1) * 64;
  const __hip_bfloat16* Ab = ctx + (size_t)b * PSTRIDE * 128;
  f32x4 acc[4][4] = {};
  for (int kc = 0; kc < 128; kc += 32) {
    bf16x8 af[4], bfr[4];
#pragma unroll
    for (int i = 0; i < 4; ++i)
      af[i] = ldfrag(Ab + (size_t)(m0 + wm + i * 16) * 128 + kc, 128, lane);
#pragma unroll
    for (int j = 0; j < 4; ++j)
      bfr[j] = ldfrag(wob + (size_t)(wn + j * 16) * 128 + kc, 128, lane);
#pragma unroll
    for (int i = 0; i < 4; ++i)
#pragma unroll
      for (int j = 0; j < 4; ++j)
        acc[i][j] = __builtin_amdgcn_mfma_f32_16x16x32_bf16(af[i], bfr[j], acc[i][j], 0, 0, 0);
  }
  int col = lane & 15, rq = lane >> 4;
  const __hip_bfloat16* lb = lidb + (size_t)b * PSTRIDE * 128;
  __hip_bfloat16* fbp = fb + (size_t)b * FBSZ;
#pragma unroll
  for (int j = 0; j < 4; ++j) {
    int n = wn + j * 16 + col;
    float bs = opb[n];
#pragma unroll
    for (int i = 0; i < 4; ++i) {
#pragma unroll
      for (int r = 0; r < 4; ++r) {
        int m = m0 + wm + i * 16 + rq * 4 + r;
        if (m < HW) {
          float v = acc[i][j][r] + bs + __bfloat162float(lb[(size_t)m * 128 + n]);
          int hh = m / WIMG, ww = m % WIMG;
          fbp[((size_t)(hh + 1) * FBROW + (ww + 1)) * 128 + n] = __float2bfloat16(v);
        }
      }
    }
  }
}

// ---------------------------------------------------------------------------
// 5) 3x3 conv 128->256 + BN + ReLU, implicit MFMA GEMM.
// ---------------------------------------------------------------------------
__global__ void __launch_bounds__(256) k_conv_mfma(
    const __hip_bfloat16* __restrict__ fb, const __hip_bfloat16* __restrict__ wcb,
    const float* __restrict__ g, const float* __restrict__ be,
    const float* __restrict__ mu, const float* __restrict__ var,
    float* __restrict__ out) {
  int bx = blockIdx.x;
  int h = bx / 3, w0 = (bx % 3) * 60;
  int b = blockIdx.z;
  int lane = threadIdx.x & 63, wid = threadIdx.x >> 6;
  int nb = wid * 64;
  const __hip_bfloat16* fbb = fb + (size_t)b * FBSZ;
  f32x4 acc[4][4] = {};
  for (int chunk = 0; chunk < 4; ++chunk) {
    int kof = chunk * 32;
    for (int dy = 0; dy < 3; ++dy) {
      const __hip_bfloat16* arow = fbb + (size_t)(h + dy) * FBROW * 128 + kof;
#pragma unroll
      for (int dx = 0; dx < 3; ++dx) {
        const __hip_bfloat16* abase = arow + (size_t)(w0 + dx) * 128;
        const __hip_bfloat16* bbase = wcb + (size_t)nb * 1152 + (dy * 3 + dx) * 128 + kof;
        bf16x8 af[4], bfr[4];
#pragma unroll
        for (int i = 0; i < 4; ++i) af[i] = ldfrag(abase + (size_t)i * 16 * 128, 128, lane);
#pragma unroll
        for (int j = 0; j < 4; ++j) bfr[j] = ldfrag(bbase + (size_t)j * 16 * 1152, 1152, lane);
#pragma unroll
        for (int i = 0; i < 4; ++i)
#pragma unroll
          for (int j = 0; j < 4; ++j)
            acc[i][j] = __builtin_amdgcn_mfma_f32_16x16x32_bf16(af[i], bfr[j], acc[i][j], 0, 0, 0);
      }
    }
  }
  int col = lane & 15, rq = lane >> 4;
#pragma unroll
  for (int j = 0; j < 4; ++j) {
    int oc = nb + j * 16 + col;
    float s = g[oc] * rsqrtf(var[oc] + 1e-5f);
    float mm = mu[oc], bb = be[oc];
#pragma unroll
    for (int i = 0; i < 4; ++i) {
      int mbase = i * 16 + rq * 4;
      if (mbase < 60) {
        float4 o4;
        o4.x = fmaxf((acc[i][j][0] - mm) * s + bb, 0.f);
        o4.y = fmaxf((acc[i][j][1] - mm) * s + bb, 0.f);
        o4.z = fmaxf((acc[i][j][2] - mm) * s + bb, 0.f);
        o4.w = fmaxf((acc[i][j][3] - mm) * s + bb, 0.f);
        *(float4*)(&out[(size_t)(b * 256 + oc) * HW + h * WIMG + w0 + mbase]) = o4;
      }
    }
  }
}

// ---------------------------------------------------------------------------
extern "C" void kernel_launch(void* const* d_in, const int* in_sizes, int n_in,
                              void* d_out, int out_size, void* d_ws, size_t ws_size,
                              hipStream_t stream) {
  const float* camera = (const float*)d_in[0];
  const float* lidar  = (const float*)d_in[1];
  const float* cam_w  = (const float*)d_in[2];
  const float* cam_g  = (const float*)d_in[3];
  const float* cam_b  = (const float*)d_in[4];
  const float* cam_m  = (const float*)d_in[5];
  const float* cam_v  = (const float*)d_in[6];
  const float* lid_w  = (const float*)d_in[7];
  const float* lid_g  = (const float*)d_in[8];
  const float* lid_b  = (const float*)d_in[9];
  const float* lid_m  = (const float*)d_in[10];
  const float* lid_v  = (const float*)d_in[11];
  const float* ipw    = (const float*)d_in[12];
  const float* ipb    = (const float*)d_in[13];
  const float* opw    = (const float*)d_in[14];
  const float* opb    = (const float*)d_in[15];
  const float* ocw    = (const float*)d_in[16];
  const float* ocg    = (const float*)d_in[17];
  const float* ocb    = (const float*)d_in[18];
  const float* ocm    = (const float*)d_in[19];
  const float* ocv    = (const float*)d_in[20];

  __hip_bfloat16* ws = (__hip_bfloat16*)d_ws;
  const size_t NP = (size_t)2 * PSTRIDE * 128;
  __hip_bfloat16* cam_bf = ws;                    // aliased by fb later
  __hip_bfloat16* lid_bf = ws + NP;
  __hip_bfloat16* qc     = ws + 2 * NP;           // q, then ctx (in-place)
  __hip_bfloat16* kvb    = ws + 3 * NP;           // [p][256], 2*NP elements
  __hip_bfloat16* wipb   = ws + 5 * NP;           // 384*128
  __hip_bfloat16* wob    = wipb + 384 * 128;      // 128*128
  __hip_bfloat16* wcb    = wob + 128 * 128;       // 256*9*128
  __hip_bfloat16* wcamb  = wcb + 256 * 9 * 128;   // 128*128 (Kpad=128)
  __hip_bfloat16* wlidb  = wcamb + 128 * 128;     // 128*256
  __hip_bfloat16* fbbuf  = cam_bf;

  dim3 blk(256);
  // weight prep
  hipLaunchKernelGGL(k_cast, dim3(192), blk, 0, stream, ipw, wipb, 384 * 128);
  hipLaunchKernelGGL(k_cast, dim3(64), blk, 0, stream, opw, wob, 128 * 128);
  hipLaunchKernelGGL(k_prepw, dim3(1152), blk, 0, stream, ocw, wcb);
  hipLaunchKernelGGL(k_prepproj, dim3(64), blk, 0, stream, cam_w, wcamb, 80, 128);
  hipLaunchKernelGGL(k_prepproj, dim3(128), blk, 0, stream, lid_w, wlidb, 256, 256);
  // projections -> pixel-major bf16 (MFMA implicit GEMM)
  dim3 gproj(254, 1, 2);
  hipLaunchKernelGGL(k_proj_mfma, gproj, blk, 0, stream,
                     camera, wcamb, cam_g, cam_b, cam_m, cam_v, cam_bf, 80, 128);
  hipLaunchKernelGGL(k_proj_mfma, gproj, blk, 0, stream,
                     lidar, wlidb, lid_g, lid_b, lid_m, lid_v, lid_bf, 256, 256);
  // qkv GEMMs
  hipLaunchKernelGGL(k_gemm_bias, dim3(254, 1, 2), blk, 0, stream,
                     lid_bf, wipb, ipb, qc, 128, 128);
  hipLaunchKernelGGL(k_gemm_bias, dim3(254, 2, 2), blk, 0, stream,
                     cam_bf, wipb + 128 * 128, ipb + 128, kvb, 128, 256);
  // attention (qc -> qc)
  hipLaunchKernelGGL(k_attn, dim3(288, 8), blk, 0, stream, qc, kvb, qc);
  // zero padded fb (aliases cam_bf, dead after kv gemm)
  int n16 = (int)((2 * FBSZ * 2) / 16);
  hipLaunchKernelGGL(k_zero, dim3((n16 + 255) / 256), blk, 0, stream, (uint4*)fbbuf, n16);
  // out-proj + residual -> fb
  hipLaunchKernelGGL(k_outproj_mfma, dim3(254, 1, 2), blk, 0, stream,
                     qc, wob, opb, lid_bf, fbbuf);
  // conv + BN + ReLU
  hipLaunchKernelGGL(k_conv_mfma, dim3(540, 1, 2), blk, 0, stream,
                     fbbuf, wcb, ocg, ocb, ocm, ocv, (float*)d_out);
}

// Round 6
// 414.344 us; speedup vs baseline: 6.8204x; 1.2116x over previous
//
#include <hip/hip_runtime.h>
#include <hip/hip_bf16.h>
#include <cmath>

#define HW      32400
#define WIMG    180
#define DD      128
#define NHEADS  8
#define DHEAD   16
#define LTOK    225
#define PSTRIDE 64928            // 32400 + slack per batch
#define FBROW   188
#define FBH     182
#define FBSZ    ((size_t)FBH * FBROW * 128)   // padded pixel-major conv input per batch

typedef __attribute__((ext_vector_type(8))) short bf16x8;
typedef __attribute__((ext_vector_type(4))) float f32x4;

union U16B { uint4 u; int4 i; bf16x8 v; };

__device__ __forceinline__ bf16x8 ldfrag(const __hip_bfloat16* p, int ld, int lane) {
  // fragment for mfma_f32_16x16x32_bf16: row = lane&15 (stride ld), k = (lane>>4)*8..+7 contiguous
  return *(const bf16x8*)(p + (size_t)(lane & 15) * ld + ((lane >> 4) << 3));
}

__device__ __forceinline__ float bf2f(unsigned int u) {
  return __uint_as_float(u << 16);
}

__device__ __forceinline__ unsigned short f2bf(float x) {
  unsigned int b = __float_as_uint(x);
  return (unsigned short)((b + 0x7fffu + ((b >> 16) & 1u)) >> 16);
}

// ---------------------------------------------------------------------------
// weight prep
// ---------------------------------------------------------------------------
__global__ void k_cast(const float* __restrict__ in, __hip_bfloat16* __restrict__ out, int n) {
  int i = blockIdx.x * 256 + threadIdx.x;
  if (i < n) out[i] = __float2bfloat16(in[i]);
}

__global__ void k_prepproj(const float* __restrict__ w, __hip_bfloat16* __restrict__ wb,
                           int C, int Kpad) {
  int i = blockIdx.x * 256 + threadIdx.x;
  if (i >= 128 * Kpad) return;
  int d = i / Kpad, c = i % Kpad;
  wb[i] = (c < C) ? __float2bfloat16(w[d * C + c]) : __float2bfloat16(0.f);
}

__global__ void k_prepw(const float* __restrict__ cw, __hip_bfloat16* __restrict__ wcb) {
  int i = blockIdx.x * 256 + threadIdx.x;
  if (i < 256 * 9 * 128) {
    int oc = i / 1152, t = (i % 1152) / 128, ic = i % 128;
    wcb[i] = __float2bfloat16(cw[(size_t)(oc * 128 + ic) * 9 + t]);
  }
}

__global__ void k_zero(uint4* __restrict__ p, int n16) {
  int i = blockIdx.x * 256 + threadIdx.x;
  if (i < n16) p[i] = make_uint4(0u, 0u, 0u, 0u);
}

// ---------------------------------------------------------------------------
// 1) 1x1 conv + BN + ReLU as implicit MFMA GEMM (unchanged from r3)
// ---------------------------------------------------------------------------
__global__ void __launch_bounds__(256) k_proj_mfma(
    const float* __restrict__ in, const __hip_bfloat16* __restrict__ wb,
    const float* __restrict__ g, const float* __restrict__ be,
    const float* __restrict__ mu, const float* __restrict__ var,
    __hip_bfloat16* __restrict__ outp, int C, int Kpad) {
  __shared__ __align__(16) __hip_bfloat16 sa[128 * 64];
  int m0 = blockIdx.x * 128;
  int b = blockIdx.z;
  int tid = threadIdx.x, lane = tid & 63, wid = tid >> 6;
  int wm = (wid >> 1) * 64, wn = (wid & 1) * 64;
  const float* inb = in + (size_t)b * C * HW;
  int sp = (tid >> 1) & 127;
  int sc4 = (tid & 1) * 4;
  int gp = m0 + sp;
  bool pok = gp < HW;
  f32x4 acc[4][4] = {};
  for (int kc = 0; kc < Kpad; kc += 64) {
    __syncthreads();
#pragma unroll
    for (int it = 0; it < 8; ++it) {
      int lc = sc4 + it * 8;
      int c = kc + lc;
      unsigned short u[4];
#pragma unroll
      for (int j = 0; j < 4; ++j) {
        float x = (pok && (c + j) < C) ? inb[(size_t)(c + j) * HW + gp] : 0.f;
        u[j] = f2bf(x);
      }
      int blk = (lc >> 3) ^ (sp & 7);
      char* dst = (char*)sa + sp * 128 + blk * 16 + (lc & 7) * 2;
      *(uint2*)dst = make_uint2(((unsigned)u[1] << 16) | u[0],
                                ((unsigned)u[3] << 16) | u[2]);
    }
    __syncthreads();
#pragma unroll
    for (int ks = 0; ks < 2; ++ks) {
      bf16x8 af[4], bfr[4];
#pragma unroll
      for (int i = 0; i < 4; ++i) {
        int pr = wm + i * 16 + (lane & 15);
        int blk = ((ks * 4 + (lane >> 4)) ^ (pr & 7));
        af[i] = *(const bf16x8*)((const char*)sa + pr * 128 + blk * 16);
      }
#pragma unroll
      for (int j = 0; j < 4; ++j)
        bfr[j] = ldfrag(wb + (size_t)(wn + j * 16) * Kpad + kc + ks * 32, Kpad, lane);
#pragma unroll
      for (int i = 0; i < 4; ++i)
#pragma unroll
        for (int j = 0; j < 4; ++j)
          acc[i][j] = __builtin_amdgcn_mfma_f32_16x16x32_bf16(af[i], bfr[j], acc[i][j], 0, 0, 0);
    }
  }
  int col = lane & 15, rq = lane >> 4;
  __hip_bfloat16* ob = outp + (size_t)b * PSTRIDE * 128;
#pragma unroll
  for (int j = 0; j < 4; ++j) {
    int d = wn + j * 16 + col;
    float s = g[d] * rsqrtf(var[d] + 1e-5f);
    float mm = mu[d], bb = be[d];
#pragma unroll
    for (int i = 0; i < 4; ++i) {
#pragma unroll
      for (int r = 0; r < 4; ++r) {
        int m = m0 + wm + i * 16 + rq * 4 + r;
        if (m < HW) {
          float y = (acc[i][j][r] - mm) * s + bb;
          ob[(size_t)m * 128 + d] = __float2bfloat16(fmaxf(y, 0.f));
        }
      }
    }
  }
}

// ---------------------------------------------------------------------------
// 2) MFMA GEMM with bias (unchanged from r3)
// ---------------------------------------------------------------------------
__global__ void __launch_bounds__(256) k_gemm_bias(
    const __hip_bfloat16* __restrict__ A, const __hip_bfloat16* __restrict__ B,
    const float* __restrict__ bias, __hip_bfloat16* __restrict__ out,
    int K, int ldout) {
  int m0 = blockIdx.x * 128, n0 = blockIdx.y * 128, b = blockIdx.z;
  int lane = threadIdx.x & 63, wid = threadIdx.x >> 6;
  int wm = (wid >> 1) * 64, wn = (wid & 1) * 64;
  const __hip_bfloat16* Ab = A + (size_t)b * PSTRIDE * K;
  f32x4 acc[4][4] = {};
  for (int kc = 0; kc < K; kc += 32) {
    bf16x8 af[4], bfr[4];
#pragma unroll
    for (int i = 0; i < 4; ++i)
      af[i] = ldfrag(Ab + (size_t)(m0 + wm + i * 16) * K + kc, K, lane);
#pragma unroll
    for (int j = 0; j < 4; ++j)
      bfr[j] = ldfrag(B + (size_t)(n0 + wn + j * 16) * K + kc, K, lane);
#pragma unroll
    for (int i = 0; i < 4; ++i)
#pragma unroll
      for (int j = 0; j < 4; ++j)
        acc[i][j] = __builtin_amdgcn_mfma_f32_16x16x32_bf16(af[i], bfr[j], acc[i][j], 0, 0, 0);
  }
  int col = lane & 15, rq = lane >> 4;
  __hip_bfloat16* ob = out + (size_t)b * PSTRIDE * ldout;
#pragma unroll
  for (int j = 0; j < 4; ++j) {
    int n = n0 + wn + j * 16 + col;
    float bs = bias[n];
#pragma unroll
    for (int i = 0; i < 4; ++i) {
#pragma unroll
      for (int r = 0; r < 4; ++r) {
        int m = m0 + wm + i * 16 + rq * 4 + r;
        if (m < HW) ob[(size_t)m * ldout + n] = __float2bfloat16(acc[i][j][r] + bs);
      }
    }
  }
}

// ---------------------------------------------------------------------------
// 3) MFMA flash attention per (bn, head).
//    S^T = mfma(Kfrag, Qfrag): D col = query (lane&15), row = key (g*4+r).
//    P redistribution via per-wave LDS transpose (P^T[q][key]), then
//    O^T = mfma(VTfrag, Pfrag): D col = query, row = d.
// ---------------------------------------------------------------------------
__global__ void __launch_bounds__(256) k_attn_mfma(
    const __hip_bfloat16* __restrict__ qc, const __hip_bfloat16* __restrict__ kvb,
    __hip_bfloat16* __restrict__ ctx) {
  __shared__ __align__(16) unsigned short ksh[240 * 32];  // [key][dh pad 32], 16B blocks XOR-swizzled
  __shared__ __align__(16) unsigned short vsh[16 * 248];  // V^T [d][key], stride 248
  __shared__ __align__(16) unsigned short psh[4 * 256];   // per-wave P^T[q][key16]
  int bn = blockIdx.x, hh = blockIdx.y;
  int b = bn / 144, rr = bn % 144, tby = rr / 12, tbx = rr % 12;
  int tid = threadIdx.x;
  int pbase = tby * 15 * WIMG + tbx * 15;
  const __hip_bfloat16* kvbase = kvb + (size_t)b * PSTRIDE * 256 + hh * 16;

  // ---- stage K (scaled by 0.25) and V^T ----
  if (tid < 240) {
    int row = tid;
    unsigned short kv16[16];
#pragma unroll
    for (int j = 0; j < 16; ++j) kv16[j] = 0;
    unsigned short vv16[16];
#pragma unroll
    for (int j = 0; j < 16; ++j) vv16[j] = 0;
    if (row < LTOK) {
      int p = pbase + (row / 15) * WIMG + (row % 15);
      const uint4* kp = (const uint4*)(kvbase + (size_t)p * 256);
      uint4 k0 = kp[0], k1 = kp[1];
      uint4 v0 = kp[16], v1 = kp[17];        // V at +128 elements = uint4 idx 16
      unsigned kw[8] = {k0.x, k0.y, k0.z, k0.w, k1.x, k1.y, k1.z, k1.w};
      unsigned vw[8] = {v0.x, v0.y, v0.z, v0.w, v1.x, v1.y, v1.z, v1.w};
#pragma unroll
      for (int j = 0; j < 8; ++j) {
        // scale K by 0.25 (power of two: exact, truncation safe)
        kv16[2 * j]     = (unsigned short)(__float_as_uint(bf2f(kw[j] & 0xffffu) * 0.25f) >> 16);
        kv16[2 * j + 1] = (unsigned short)(__float_as_uint(bf2f(kw[j] >> 16) * 0.25f) >> 16);
        vv16[2 * j]     = (unsigned short)(vw[j] & 0xffffu);
        vv16[2 * j + 1] = (unsigned short)(vw[j] >> 16);
      }
    }
    // K row: 4 16B blocks at row*64 + 16*(blk ^ (row&3)); blk=2,3 zero (d padding)
    char* kbase = (char*)ksh + row * 64;
    uint4 zz = make_uint4(0, 0, 0, 0);
    *(uint4*)(kbase + ((0 ^ (row & 3)) << 4)) = ((uint4*)kv16)[0];
    *(uint4*)(kbase + ((1 ^ (row & 3)) << 4)) = ((uint4*)kv16)[1];
    *(uint4*)(kbase + ((2 ^ (row & 3)) << 4)) = zz;
    *(uint4*)(kbase + ((3 ^ (row & 3)) << 4)) = zz;
    // V^T scatter
#pragma unroll
    for (int d = 0; d < 16; ++d) vsh[d * 248 + row] = vv16[d];
  }
  __syncthreads();

  int lane = tid & 63, wid = tid >> 6;
  int g = lane >> 4, q15 = lane & 15;
  int wq0 = wid * 64;
  char* pw_base = (char*)psh + wid * 512;    // this wave's 16x16 bf16 P^T tile

  // Q fragments (4 q-tiles per wave); groups 2,3 are the k-padding -> zero
  bf16x8 qf[4];
#pragma unroll
  for (int i = 0; i < 4; ++i) {
    int q = wq0 + i * 16 + q15;
    int qq = q < LTOK ? q : 0;
    int p = pbase + (qq / 15) * WIMG + (qq % 15);
    U16B u; u.u = make_uint4(0, 0, 0, 0);
    if (g < 2) u.u = *(const uint4*)(qc + ((size_t)b * PSTRIDE + p) * 128 + hh * 16 + g * 8);
    qf[i] = u.v;
  }

  float m_[4], ls[4];
  f32x4 oac[4] = {};
#pragma unroll
  for (int i = 0; i < 4; ++i) { m_[i] = -3.0e38f; ls[i] = 0.f; }
  const f32x4 zacc = {};

  for (int ck = 0; ck < 15; ++ck) {
    int rowb = ck * 16 + q15;
    bf16x8 kf = *(const bf16x8*)((const char*)ksh + rowb * 64 + ((g ^ (rowb & 3)) << 4));
    U16B vu; vu.u = make_uint4(0, 0, 0, 0);
    if (g < 2) vu.u = *(const uint4*)((const char*)vsh + (q15 * 248 + ck * 16 + g * 8) * 2);
    bf16x8 vf = vu.v;
#pragma unroll
    for (int i = 0; i < 4; ++i) {
      f32x4 st = __builtin_amdgcn_mfma_f32_16x16x32_bf16(kf, qf[i], zacc, 0, 0, 0);
      float s0 = st[0], s1 = st[1], s2 = st[2], s3 = st[3];
      if (ck == 14) {                        // keys 224..239: only key 224 valid
        s0 = (g == 0) ? s0 : -3.0e38f;
        s1 = -3.0e38f; s2 = -3.0e38f; s3 = -3.0e38f;
      }
      float cm = fmaxf(fmaxf(s0, s1), fmaxf(s2, s3));
      cm = fmaxf(cm, __shfl_xor(cm, 16));
      cm = fmaxf(cm, __shfl_xor(cm, 32));
      float mn = fmaxf(m_[i], cm);
      float corr = __expf(m_[i] - mn);
      float p0 = __expf(s0 - mn), p1 = __expf(s1 - mn);
      float p2 = __expf(s2 - mn), p3 = __expf(s3 - mn);
      float ps = (p0 + p1) + (p2 + p3);
      ps += __shfl_xor(ps, 16);
      ps += __shfl_xor(ps, 32);
      ls[i] = ls[i] * corr + ps;
      m_[i] = mn;
      // ---- P redistribution via LDS: write P^T[q=q15][key=g*4+r] ----
      unsigned w0 = (unsigned)f2bf(p0) | ((unsigned)f2bf(p1) << 16);
      unsigned w1 = (unsigned)f2bf(p2) | ((unsigned)f2bf(p3) << 16);
      *(uint2*)(pw_base + q15 * 32 + g * 8) = make_uint2(w0, w1);
      // read B-frag: lane (g,q15) takes P^T[q15][8g..8g+7]; g>=2 -> k padding zero
      U16B pu; pu.u = make_uint4(0, 0, 0, 0);
      if (g < 2) pu.u = *(const uint4*)(pw_base + q15 * 32 + g * 16);
      f32x4 oc = oac[i];
      oc[0] *= corr; oc[1] *= corr; oc[2] *= corr; oc[3] *= corr;
      oac[i] = __builtin_amdgcn_mfma_f32_16x16x32_bf16(vf, pu.v, oc, 0, 0, 0);
    }
  }

  // ---- epilogue: normalize and store (lane owns ctx[q][hh*16 + g*4 .. +3]) ----
  __hip_bfloat16* cb = ctx + (size_t)b * PSTRIDE * 128 + hh * 16;
#pragma unroll
  for (int i = 0; i < 4; ++i) {
    float inv = 1.f / ls[i];
    int qo = wq0 + i * 16 + q15;
    if (qo < LTOK) {
      unsigned lo = (unsigned)f2bf(oac[i][0] * inv) | ((unsigned)f2bf(oac[i][1] * inv) << 16);
      unsigned hi = (unsigned)f2bf(oac[i][2] * inv) | ((unsigned)f2bf(oac[i][3] * inv) << 16);
      int p = pbase + (qo / 15) * WIMG + (qo % 15);
      *(uint2*)(cb + (size_t)p * 128 + g * 4) = make_uint2(lo, hi);
    }
  }
}

// ---------------------------------------------------------------------------
// 4) out-proj MFMA GEMM + bias + residual -> padded fb bf16 (unchanged)
// ---------------------------------------------------------------------------
__global__ void __launch_bounds__(256) k_outproj_mfma(
    const __hip_bfloat16* __restrict__ ctx, const __hip_bfloat16* __restrict__ wob,
    const float* __restrict__ opb, const __hip_bfloat16* __restrict__ lidb,
    __hip_bfloat16* __restrict__ fb) {
  int m0 = blockIdx.x * 128, b = blockIdx.z;
  int lane = threadIdx.x & 63, wid = threadIdx.x >> 6;
  int wm = (wid >> 1) * 64, wn = (wid & 1) * 64;
  const __hip_bfloat16* Ab = ctx + (size_t)b * PSTRIDE * 128;
  f32x4 acc[4][4] = {};
  for (int kc = 0; kc < 128; kc += 32) {
    bf16x8 af[4], bfr[4];
#pragma unroll
    for (int i = 0; i < 4; ++i)
      af[i] = ldfrag(Ab + (size_t)(m0 + wm + i * 16) * 128 + kc, 128, lane);
#pragma unroll
    for (int j = 0; j < 4; ++j)
      bfr[j] = ldfrag(wob + (size_t)(wn + j * 16) * 128 + kc, 128, lane);
#pragma unroll
    for (int i = 0; i < 4; ++i)
#pragma unroll
      for (int j = 0; j < 4; ++j)
        acc[i][j] = __builtin_amdgcn_mfma_f32_16x16x32_bf16(af[i], bfr[j], acc[i][j], 0, 0, 0);
  }
  int col = lane & 15, rq = lane >> 4;
  const __hip_bfloat16* lb = lidb + (size_t)b * PSTRIDE * 128;
  __hip_bfloat16* fbp = fb + (size_t)b * FBSZ;
#pragma unroll
  for (int j = 0; j < 4; ++j) {
    int n = wn + j * 16 + col;
    float bs = opb[n];
#pragma unroll
    for (int i = 0; i < 4; ++i) {
#pragma unroll
      for (int r = 0; r < 4; ++r) {
        int m = m0 + wm + i * 16 + rq * 4 + r;
        if (m < HW) {
          float v = acc[i][j][r] + bs + __bfloat162float(lb[(size_t)m * 128 + n]);
          int hhh = m / WIMG, www = m % WIMG;
          fbp[((size_t)(hhh + 1) * FBROW + (www + 1)) * 128 + n] = __float2bfloat16(v);
        }
      }
    }
  }
}

// ---------------------------------------------------------------------------
// 5) 3x3 conv 128->256 + BN + ReLU, implicit MFMA GEMM (unchanged)
// ---------------------------------------------------------------------------
__global__ void __launch_bounds__(256) k_conv_mfma(
    const __hip_bfloat16* __restrict__ fb, const __hip_bfloat16* __restrict__ wcb,
    const float* __restrict__ g, const float* __restrict__ be,
    const float* __restrict__ mu, const float* __restrict__ var,
    float* __restrict__ out) {
  int bx = blockIdx.x;
  int h = bx / 3, w0 = (bx % 3) * 60;
  int b = blockIdx.z;
  int lane = threadIdx.x & 63, wid = threadIdx.x >> 6;
  int nb = wid * 64;
  const __hip_bfloat16* fbb = fb + (size_t)b * FBSZ;
  f32x4 acc[4][4] = {};
  for (int chunk = 0; chunk < 4; ++chunk) {
    int kof = chunk * 32;
    for (int dy = 0; dy < 3; ++dy) {
      const __hip_bfloat16* arow = fbb + (size_t)(h + dy) * FBROW * 128 + kof;
#pragma unroll
      for (int dx = 0; dx < 3; ++dx) {
        const __hip_bfloat16* abase = arow + (size_t)(w0 + dx) * 128;
        const __hip_bfloat16* bbase = wcb + (size_t)nb * 1152 + (dy * 3 + dx) * 128 + kof;
        bf16x8 af[4], bfr[4];
#pragma unroll
        for (int i = 0; i < 4; ++i) af[i] = ldfrag(abase + (size_t)i * 16 * 128, 128, lane);
#pragma unroll
        for (int j = 0; j < 4; ++j) bfr[j] = ldfrag(bbase + (size_t)j * 16 * 1152, 1152, lane);
#pragma unroll
        for (int i = 0; i < 4; ++i)
#pragma unroll
          for (int j = 0; j < 4; ++j)
            acc[i][j] = __builtin_amdgcn_mfma_f32_16x16x32_bf16(af[i], bfr[j], acc[i][j], 0, 0, 0);
      }
    }
  }
  int col = lane & 15, rq = lane >> 4;
#pragma unroll
  for (int j = 0; j < 4; ++j) {
    int oc = nb + j * 16 + col;
    float s = g[oc] * rsqrtf(var[oc] + 1e-5f);
    float mm = mu[oc], bb = be[oc];
#pragma unroll
    for (int i = 0; i < 4; ++i) {
      int mbase = i * 16 + rq * 4;
      if (mbase < 60) {
        float4 o4;
        o4.x = fmaxf((acc[i][j][0] - mm) * s + bb, 0.f);
        o4.y = fmaxf((acc[i][j][1] - mm) * s + bb, 0.f);
        o4.z = fmaxf((acc[i][j][2] - mm) * s + bb, 0.f);
        o4.w = fmaxf((acc[i][j][3] - mm) * s + bb, 0.f);
        *(float4*)(&out[(size_t)(b * 256 + oc) * HW + h * WIMG + w0 + mbase]) = o4;
      }
    }
  }
}

// ---------------------------------------------------------------------------
extern "C" void kernel_launch(void* const* d_in, const int* in_sizes, int n_in,
                              void* d_out, int out_size, void* d_ws, size_t ws_size,
                              hipStream_t stream) {
  const float* camera = (const float*)d_in[0];
  const float* lidar  = (const float*)d_in[1];
  const float* cam_w  = (const float*)d_in[2];
  const float* cam_g  = (const float*)d_in[3];
  const float* cam_b  = (const float*)d_in[4];
  const float* cam_m  = (const float*)d_in[5];
  const float* cam_v  = (const float*)d_in[6];
  const float* lid_w  = (const float*)d_in[7];
  const float* lid_g  = (const float*)d_in[8];
  const float* lid_b  = (const float*)d_in[9];
  const float* lid_m  = (const float*)d_in[10];
  const float* lid_v  = (const float*)d_in[11];
  const float* ipw    = (const float*)d_in[12];
  const float* ipb    = (const float*)d_in[13];
  const float* opw    = (const float*)d_in[14];
  const float* opb    = (const float*)d_in[15];
  const float* ocw    = (const float*)d_in[16];
  const float* ocg    = (const float*)d_in[17];
  const float* ocb    = (const float*)d_in[18];
  const float* ocm    = (const float*)d_in[19];
  const float* ocv    = (const float*)d_in[20];

  __hip_bfloat16* ws = (__hip_bfloat16*)d_ws;
  const size_t NP = (size_t)2 * PSTRIDE * 128;
  __hip_bfloat16* cam_bf = ws;                    // aliased by fb later
  __hip_bfloat16* lid_bf = ws + NP;
  __hip_bfloat16* qc     = ws + 2 * NP;           // q, then ctx (in-place)
  __hip_bfloat16* kvb    = ws + 3 * NP;           // [p][256], 2*NP elements
  __hip_bfloat16* wipb   = ws + 5 * NP;           // 384*128
  __hip_bfloat16* wob    = wipb + 384 * 128;      // 128*128
  __hip_bfloat16* wcb    = wob + 128 * 128;       // 256*9*128
  __hip_bfloat16* wcamb  = wcb + 256 * 9 * 128;   // 128*128 (Kpad=128)
  __hip_bfloat16* wlidb  = wcamb + 128 * 128;     // 128*256
  __hip_bfloat16* fbbuf  = cam_bf;

  dim3 blk(256);
  // weight prep
  hipLaunchKernelGGL(k_cast, dim3(192), blk, 0, stream, ipw, wipb, 384 * 128);
  hipLaunchKernelGGL(k_cast, dim3(64), blk, 0, stream, opw, wob, 128 * 128);
  hipLaunchKernelGGL(k_prepw, dim3(1152), blk, 0, stream, ocw, wcb);
  hipLaunchKernelGGL(k_prepproj, dim3(64), blk, 0, stream, cam_w, wcamb, 80, 128);
  hipLaunchKernelGGL(k_prepproj, dim3(128), blk, 0, stream, lid_w, wlidb, 256, 256);
  // projections -> pixel-major bf16 (MFMA implicit GEMM)
  dim3 gproj(254, 1, 2);
  hipLaunchKernelGGL(k_proj_mfma, gproj, blk, 0, stream,
                     camera, wcamb, cam_g, cam_b, cam_m, cam_v, cam_bf, 80, 128);
  hipLaunchKernelGGL(k_proj_mfma, gproj, blk, 0, stream,
                     lidar, wlidb, lid_g, lid_b, lid_m, lid_v, lid_bf, 256, 256);
  // qkv GEMMs
  hipLaunchKernelGGL(k_gemm_bias, dim3(254, 1, 2), blk, 0, stream,
                     lid_bf, wipb, ipb, qc, 128, 128);
  hipLaunchKernelGGL(k_gemm_bias, dim3(254, 2, 2), blk, 0, stream,
                     cam_bf, wipb + 128 * 128, ipb + 128, kvb, 128, 256);
  // attention (qc -> qc in place)
  hipLaunchKernelGGL(k_attn_mfma, dim3(288, 8), blk, 0, stream, qc, kvb, qc);
  // zero padded fb (aliases cam_bf, dead after kv gemm)
  int n16 = (int)((2 * FBSZ * 2) / 16);
  hipLaunchKernelGGL(k_zero, dim3((n16 + 255) / 256), blk, 0, stream, (uint4*)fbbuf, n16);
  // out-proj + residual -> fb
  hipLaunchKernelGGL(k_outproj_mfma, dim3(254, 1, 2), blk, 0, stream,
                     qc, wob, opb, lid_bf, fbbuf);
  // conv + BN + ReLU
  hipLaunchKernelGGL(k_conv_mfma, dim3(540, 1, 2), blk, 0, stream,
                     fbbuf, wcb, ocg, ocb, ocm, ocv, (float*)d_out);
}

// Round 7
// 400.283 us; speedup vs baseline: 7.0600x; 1.0351x over previous
//
#include <hip/hip_runtime.h>
#include <hip/hip_bf16.h>
#include <cmath>

#define HW      32400
#define WIMG    180
#define DD      128
#define NHEADS  8
#define DHEAD   16
#define LTOK    225
#define PSTRIDE 64928            // 32400 + slack per batch
#define FBROW   188
#define FBH     182
#define FBSZ    ((size_t)FBH * FBROW * 128)   // padded pixel-major conv input per batch

typedef __attribute__((ext_vector_type(8))) short bf16x8;
typedef __attribute__((ext_vector_type(4))) float f32x4;

union U16B { uint4 u; int4 i; bf16x8 v; };

__device__ __forceinline__ bf16x8 ldfrag(const __hip_bfloat16* p, int ld, int lane) {
  // fragment for mfma_f32_16x16x32_bf16: row = lane&15 (stride ld), k = (lane>>4)*8..+7 contiguous
  return *(const bf16x8*)(p + (size_t)(lane & 15) * ld + ((lane >> 4) << 3));
}

__device__ __forceinline__ float bf2f(unsigned int u) {
  return __uint_as_float(u << 16);
}

__device__ __forceinline__ unsigned short f2bf(float x) {
  unsigned int b = __float_as_uint(x);
  return (unsigned short)((b + 0x7fffu + ((b >> 16) & 1u)) >> 16);
}

// ---------------------------------------------------------------------------
// weight prep
// ---------------------------------------------------------------------------
__global__ void k_cast(const float* __restrict__ in, __hip_bfloat16* __restrict__ out, int n) {
  int i = blockIdx.x * 256 + threadIdx.x;
  if (i < n) out[i] = __float2bfloat16(in[i]);
}

__global__ void k_prepproj(const float* __restrict__ w, __hip_bfloat16* __restrict__ wb,
                           int C, int Kpad) {
  int i = blockIdx.x * 256 + threadIdx.x;
  if (i >= 128 * Kpad) return;
  int d = i / Kpad, c = i % Kpad;
  wb[i] = (c < C) ? __float2bfloat16(w[d * C + c]) : __float2bfloat16(0.f);
}

__global__ void k_prepw(const float* __restrict__ cw, __hip_bfloat16* __restrict__ wcb) {
  int i = blockIdx.x * 256 + threadIdx.x;
  if (i < 256 * 9 * 128) {
    int oc = i / 1152, t = (i % 1152) / 128, ic = i % 128;
    wcb[i] = __float2bfloat16(cw[(size_t)(oc * 128 + ic) * 9 + t]);
  }
}

__global__ void k_zero(uint4* __restrict__ p, int n16) {
  int i = blockIdx.x * 256 + threadIdx.x;
  if (i < n16) p[i] = make_uint4(0u, 0u, 0u, 0u);
}

// ---------------------------------------------------------------------------
// 1) 1x1 conv + BN + ReLU as implicit MFMA GEMM (unchanged)
// ---------------------------------------------------------------------------
__global__ void __launch_bounds__(256) k_proj_mfma(
    const float* __restrict__ in, const __hip_bfloat16* __restrict__ wb,
    const float* __restrict__ g, const float* __restrict__ be,
    const float* __restrict__ mu, const float* __restrict__ var,
    __hip_bfloat16* __restrict__ outp, int C, int Kpad) {
  __shared__ __align__(16) __hip_bfloat16 sa[128 * 64];
  int m0 = blockIdx.x * 128;
  int b = blockIdx.z;
  int tid = threadIdx.x, lane = tid & 63, wid = tid >> 6;
  int wm = (wid >> 1) * 64, wn = (wid & 1) * 64;
  const float* inb = in + (size_t)b * C * HW;
  int sp = (tid >> 1) & 127;
  int sc4 = (tid & 1) * 4;
  int gp = m0 + sp;
  bool pok = gp < HW;
  f32x4 acc[4][4] = {};
  for (int kc = 0; kc < Kpad; kc += 64) {
    __syncthreads();
#pragma unroll
    for (int it = 0; it < 8; ++it) {
      int lc = sc4 + it * 8;
      int c = kc + lc;
      unsigned short u[4];
#pragma unroll
      for (int j = 0; j < 4; ++j) {
        float x = (pok && (c + j) < C) ? inb[(size_t)(c + j) * HW + gp] : 0.f;
        u[j] = f2bf(x);
      }
      int blk = (lc >> 3) ^ (sp & 7);
      char* dst = (char*)sa + sp * 128 + blk * 16 + (lc & 7) * 2;
      *(uint2*)dst = make_uint2(((unsigned)u[1] << 16) | u[0],
                                ((unsigned)u[3] << 16) | u[2]);
    }
    __syncthreads();
#pragma unroll
    for (int ks = 0; ks < 2; ++ks) {
      bf16x8 af[4], bfr[4];
#pragma unroll
      for (int i = 0; i < 4; ++i) {
        int pr = wm + i * 16 + (lane & 15);
        int blk = ((ks * 4 + (lane >> 4)) ^ (pr & 7));
        af[i] = *(const bf16x8*)((const char*)sa + pr * 128 + blk * 16);
      }
#pragma unroll
      for (int j = 0; j < 4; ++j)
        bfr[j] = ldfrag(wb + (size_t)(wn + j * 16) * Kpad + kc + ks * 32, Kpad, lane);
#pragma unroll
      for (int i = 0; i < 4; ++i)
#pragma unroll
        for (int j = 0; j < 4; ++j)
          acc[i][j] = __builtin_amdgcn_mfma_f32_16x16x32_bf16(af[i], bfr[j], acc[i][j], 0, 0, 0);
    }
  }
  int col = lane & 15, rq = lane >> 4;
  __hip_bfloat16* ob = outp + (size_t)b * PSTRIDE * 128;
#pragma unroll
  for (int j = 0; j < 4; ++j) {
    int d = wn + j * 16 + col;
    float s = g[d] * rsqrtf(var[d] + 1e-5f);
    float mm = mu[d], bb = be[d];
#pragma unroll
    for (int i = 0; i < 4; ++i) {
#pragma unroll
      for (int r = 0; r < 4; ++r) {
        int m = m0 + wm + i * 16 + rq * 4 + r;
        if (m < HW) {
          float y = (acc[i][j][r] - mm) * s + bb;
          ob[(size_t)m * 128 + d] = __float2bfloat16(fmaxf(y, 0.f));
        }
      }
    }
  }
}

// ---------------------------------------------------------------------------
// 2) MFMA GEMM with bias (unchanged)
// ---------------------------------------------------------------------------
__global__ void __launch_bounds__(256) k_gemm_bias(
    const __hip_bfloat16* __restrict__ A, const __hip_bfloat16* __restrict__ B,
    const float* __restrict__ bias, __hip_bfloat16* __restrict__ out,
    int K, int ldout) {
  int m0 = blockIdx.x * 128, n0 = blockIdx.y * 128, b = blockIdx.z;
  int lane = threadIdx.x & 63, wid = threadIdx.x >> 6;
  int wm = (wid >> 1) * 64, wn = (wid & 1) * 64;
  const __hip_bfloat16* Ab = A + (size_t)b * PSTRIDE * K;
  f32x4 acc[4][4] = {};
  for (int kc = 0; kc < K; kc += 32) {
    bf16x8 af[4], bfr[4];
#pragma unroll
    for (int i = 0; i < 4; ++i)
      af[i] = ldfrag(Ab + (size_t)(m0 + wm + i * 16) * K + kc, K, lane);
#pragma unroll
    for (int j = 0; j < 4; ++j)
      bfr[j] = ldfrag(B + (size_t)(n0 + wn + j * 16) * K + kc, K, lane);
#pragma unroll
    for (int i = 0; i < 4; ++i)
#pragma unroll
      for (int j = 0; j < 4; ++j)
        acc[i][j] = __builtin_amdgcn_mfma_f32_16x16x32_bf16(af[i], bfr[j], acc[i][j], 0, 0, 0);
  }
  int col = lane & 15, rq = lane >> 4;
  __hip_bfloat16* ob = out + (size_t)b * PSTRIDE * ldout;
#pragma unroll
  for (int j = 0; j < 4; ++j) {
    int n = n0 + wn + j * 16 + col;
    float bs = bias[n];
#pragma unroll
    for (int i = 0; i < 4; ++i) {
#pragma unroll
      for (int r = 0; r < 4; ++r) {
        int m = m0 + wm + i * 16 + rq * 4 + r;
        if (m < HW) ob[(size_t)m * ldout + n] = __float2bfloat16(acc[i][j][r] + bs);
      }
    }
  }
}

// ---------------------------------------------------------------------------
// 3) MFMA flash attention per (bn, head) (unchanged from r6)
// ---------------------------------------------------------------------------
__global__ void __launch_bounds__(256) k_attn_mfma(
    const __hip_bfloat16* __restrict__ qc, const __hip_bfloat16* __restrict__ kvb,
    __hip_bfloat16* __restrict__ ctx) {
  __shared__ __align__(16) unsigned short ksh[240 * 32];  // [key][dh pad 32], swizzled
  __shared__ __align__(16) unsigned short vsh[16 * 248];  // V^T [d][key]
  __shared__ __align__(16) unsigned short psh[4 * 256];   // per-wave P^T[q][key16]
  int bn = blockIdx.x, hh = blockIdx.y;
  int b = bn / 144, rr = bn % 144, tby = rr / 12, tbx = rr % 12;
  int tid = threadIdx.x;
  int pbase = tby * 15 * WIMG + tbx * 15;
  const __hip_bfloat16* kvbase = kvb + (size_t)b * PSTRIDE * 256 + hh * 16;

  if (tid < 240) {
    int row = tid;
    unsigned short kv16[16];
#pragma unroll
    for (int j = 0; j < 16; ++j) kv16[j] = 0;
    unsigned short vv16[16];
#pragma unroll
    for (int j = 0; j < 16; ++j) vv16[j] = 0;
    if (row < LTOK) {
      int p = pbase + (row / 15) * WIMG + (row % 15);
      const uint4* kp = (const uint4*)(kvbase + (size_t)p * 256);
      uint4 k0 = kp[0], k1 = kp[1];
      uint4 v0 = kp[16], v1 = kp[17];
      unsigned kw[8] = {k0.x, k0.y, k0.z, k0.w, k1.x, k1.y, k1.z, k1.w};
      unsigned vw[8] = {v0.x, v0.y, v0.z, v0.w, v1.x, v1.y, v1.z, v1.w};
#pragma unroll
      for (int j = 0; j < 8; ++j) {
        kv16[2 * j]     = (unsigned short)(__float_as_uint(bf2f(kw[j] & 0xffffu) * 0.25f) >> 16);
        kv16[2 * j + 1] = (unsigned short)(__float_as_uint(bf2f(kw[j] >> 16) * 0.25f) >> 16);
        vv16[2 * j]     = (unsigned short)(vw[j] & 0xffffu);
        vv16[2 * j + 1] = (unsigned short)(vw[j] >> 16);
      }
    }
    char* kbase = (char*)ksh + row * 64;
    uint4 zz = make_uint4(0, 0, 0, 0);
    *(uint4*)(kbase + ((0 ^ (row & 3)) << 4)) = ((uint4*)kv16)[0];
    *(uint4*)(kbase + ((1 ^ (row & 3)) << 4)) = ((uint4*)kv16)[1];
    *(uint4*)(kbase + ((2 ^ (row & 3)) << 4)) = zz;
    *(uint4*)(kbase + ((3 ^ (row & 3)) << 4)) = zz;
#pragma unroll
    for (int d = 0; d < 16; ++d) vsh[d * 248 + row] = vv16[d];
  }
  __syncthreads();

  int lane = tid & 63, wid = tid >> 6;
  int g = lane >> 4, q15 = lane & 15;
  int wq0 = wid * 64;
  char* pw_base = (char*)psh + wid * 512;

  bf16x8 qf[4];
#pragma unroll
  for (int i = 0; i < 4; ++i) {
    int q = wq0 + i * 16 + q15;
    int qq = q < LTOK ? q : 0;
    int p = pbase + (qq / 15) * WIMG + (qq % 15);
    U16B u; u.u = make_uint4(0, 0, 0, 0);
    if (g < 2) u.u = *(const uint4*)(qc + ((size_t)b * PSTRIDE + p) * 128 + hh * 16 + g * 8);
    qf[i] = u.v;
  }

  float m_[4], ls[4];
  f32x4 oac[4] = {};
#pragma unroll
  for (int i = 0; i < 4; ++i) { m_[i] = -3.0e38f; ls[i] = 0.f; }
  const f32x4 zacc = {};

  for (int ck = 0; ck < 15; ++ck) {
    int rowb = ck * 16 + q15;
    bf16x8 kf = *(const bf16x8*)((const char*)ksh + rowb * 64 + ((g ^ (rowb & 3)) << 4));
    U16B vu; vu.u = make_uint4(0, 0, 0, 0);
    if (g < 2) vu.u = *(const uint4*)((const char*)vsh + (q15 * 248 + ck * 16 + g * 8) * 2);
    bf16x8 vf = vu.v;
#pragma unroll
    for (int i = 0; i < 4; ++i) {
      f32x4 st = __builtin_amdgcn_mfma_f32_16x16x32_bf16(kf, qf[i], zacc, 0, 0, 0);
      float s0 = st[0], s1 = st[1], s2 = st[2], s3 = st[3];
      if (ck == 14) {
        s0 = (g == 0) ? s0 : -3.0e38f;
        s1 = -3.0e38f; s2 = -3.0e38f; s3 = -3.0e38f;
      }
      float cm = fmaxf(fmaxf(s0, s1), fmaxf(s2, s3));
      cm = fmaxf(cm, __shfl_xor(cm, 16));
      cm = fmaxf(cm, __shfl_xor(cm, 32));
      float mn = fmaxf(m_[i], cm);
      float corr = __expf(m_[i] - mn);
      float p0 = __expf(s0 - mn), p1 = __expf(s1 - mn);
      float p2 = __expf(s2 - mn), p3 = __expf(s3 - mn);
      float ps = (p0 + p1) + (p2 + p3);
      ps += __shfl_xor(ps, 16);
      ps += __shfl_xor(ps, 32);
      ls[i] = ls[i] * corr + ps;
      m_[i] = mn;
      unsigned w0 = (unsigned)f2bf(p0) | ((unsigned)f2bf(p1) << 16);
      unsigned w1 = (unsigned)f2bf(p2) | ((unsigned)f2bf(p3) << 16);
      *(uint2*)(pw_base + q15 * 32 + g * 8) = make_uint2(w0, w1);
      U16B pu; pu.u = make_uint4(0, 0, 0, 0);
      if (g < 2) pu.u = *(const uint4*)(pw_base + q15 * 32 + g * 16);
      f32x4 oc = oac[i];
      oc[0] *= corr; oc[1] *= corr; oc[2] *= corr; oc[3] *= corr;
      oac[i] = __builtin_amdgcn_mfma_f32_16x16x32_bf16(vf, pu.v, oc, 0, 0, 0);
    }
  }

  __hip_bfloat16* cb = ctx + (size_t)b * PSTRIDE * 128 + hh * 16;
#pragma unroll
  for (int i = 0; i < 4; ++i) {
    float inv = 1.f / ls[i];
    int qo = wq0 + i * 16 + q15;
    if (qo < LTOK) {
      unsigned lo = (unsigned)f2bf(oac[i][0] * inv) | ((unsigned)f2bf(oac[i][1] * inv) << 16);
      unsigned hi = (unsigned)f2bf(oac[i][2] * inv) | ((unsigned)f2bf(oac[i][3] * inv) << 16);
      int p = pbase + (qo / 15) * WIMG + (qo % 15);
      *(uint2*)(cb + (size_t)p * 128 + g * 4) = make_uint2(lo, hi);
    }
  }
}

// ---------------------------------------------------------------------------
// 4) out-proj MFMA GEMM + bias + residual -> padded fb bf16 (unchanged)
// ---------------------------------------------------------------------------
__global__ void __launch_bounds__(256) k_outproj_mfma(
    const __hip_bfloat16* __restrict__ ctx, const __hip_bfloat16* __restrict__ wob,
    const float* __restrict__ opb, const __hip_bfloat16* __restrict__ lidb,
    __hip_bfloat16* __restrict__ fb) {
  int m0 = blockIdx.x * 128, b = blockIdx.z;
  int lane = threadIdx.x & 63, wid = threadIdx.x >> 6;
  int wm = (wid >> 1) * 64, wn = (wid & 1) * 64;
  const __hip_bfloat16* Ab = ctx + (size_t)b * PSTRIDE * 128;
  f32x4 acc[4][4] = {};
  for (int kc = 0; kc < 128; kc += 32) {
    bf16x8 af[4], bfr[4];
#pragma unroll
    for (int i = 0; i < 4; ++i)
      af[i] = ldfrag(Ab + (size_t)(m0 + wm + i * 16) * 128 + kc, 128, lane);
#pragma unroll
    for (int j = 0; j < 4; ++j)
      bfr[j] = ldfrag(wob + (size_t)(wn + j * 16) * 128 + kc, 128, lane);
#pragma unroll
    for (int i = 0; i < 4; ++i)
#pragma unroll
      for (int j = 0; j < 4; ++j)
        acc[i][j] = __builtin_amdgcn_mfma_f32_16x16x32_bf16(af[i], bfr[j], acc[i][j], 0, 0, 0);
  }
  int col = lane & 15, rq = lane >> 4;
  const __hip_bfloat16* lb = lidb + (size_t)b * PSTRIDE * 128;
  __hip_bfloat16* fbp = fb + (size_t)b * FBSZ;
#pragma unroll
  for (int j = 0; j < 4; ++j) {
    int n = wn + j * 16 + col;
    float bs = opb[n];
#pragma unroll
    for (int i = 0; i < 4; ++i) {
#pragma unroll
      for (int r = 0; r < 4; ++r) {
        int m = m0 + wm + i * 16 + rq * 4 + r;
        if (m < HW) {
          float v = acc[i][j][r] + bs + __bfloat162float(lb[(size_t)m * 128 + n]);
          int hhh = m / WIMG, www = m % WIMG;
          fbp[((size_t)(hhh + 1) * FBROW + (www + 1)) * 128 + n] = __float2bfloat16(v);
        }
      }
    }
  }
}

// ---------------------------------------------------------------------------
// 5) 3x3 conv 128->256 + BN + ReLU: 30-px strips, A staged once in LDS
//    (XOR-swizzled), barrier-free main loop, 2160 blocks for occupancy.
// ---------------------------------------------------------------------------
__global__ void __launch_bounds__(256) k_conv_mfma(
    const __hip_bfloat16* __restrict__ fb, const __hip_bfloat16* __restrict__ wcb,
    const float* __restrict__ g, const float* __restrict__ be,
    const float* __restrict__ mu, const float* __restrict__ var,
    float* __restrict__ out) {
  __shared__ __align__(16) uint4 sa[100 * 16];   // [row_px 0..95][blk], swizzled; 4 pad rows
  int bx = blockIdx.x;
  int h = bx / 6, strip = bx % 6;
  int w0 = strip * 30;
  int b = blockIdx.z;
  int tid = threadIdx.x, lane = tid & 63, wid = tid >> 6;
  int nb = wid * 64;
  const __hip_bfloat16* fbb = fb + (size_t)b * FBSZ;
  // ---- stage A once: input rows h-1..h+1 (padded h..h+2), cols w0-1..w0+30 ----
#pragma unroll
  for (int it = 0; it < 6; ++it) {
    int li = tid + it * 256;
    int row_px = li >> 4, blk = li & 15;
    int dy = row_px >> 5, px = row_px & 31;
    const uint4* src = (const uint4*)(fbb + ((size_t)(h + dy) * FBROW + (w0 + px)) * 128) + blk;
    sa[row_px * 16 + (blk ^ (px & 7))] = *src;
  }
  __syncthreads();
  int q15 = lane & 15, kg = lane >> 4;
  f32x4 acc[2][4] = {};
  for (int chunk = 0; chunk < 4; ++chunk) {
    int kof = chunk * 32;
    int kblk = (kof >> 3) + kg;
#pragma unroll
    for (int dy = 0; dy < 3; ++dy) {
#pragma unroll
      for (int dx = 0; dx < 3; ++dx) {
        const __hip_bfloat16* bbase = wcb + (size_t)nb * 1152 + (dy * 3 + dx) * 128 + kof;
        bf16x8 af[2], bfr[4];
#pragma unroll
        for (int i = 0; i < 2; ++i) {
          int pxl = i * 16 + q15 + dx;
          int rp = dy * 32 + pxl;
          af[i] = *(const bf16x8*)&sa[rp * 16 + (kblk ^ (pxl & 7))];
        }
#pragma unroll
        for (int j = 0; j < 4; ++j)
          bfr[j] = ldfrag(bbase + (size_t)j * 16 * 1152, 1152, lane);
#pragma unroll
        for (int i = 0; i < 2; ++i)
#pragma unroll
          for (int j = 0; j < 4; ++j)
            acc[i][j] = __builtin_amdgcn_mfma_f32_16x16x32_bf16(af[i], bfr[j], acc[i][j], 0, 0, 0);
      }
    }
  }
  int col = q15, rq = kg;
#pragma unroll
  for (int j = 0; j < 4; ++j) {
    int oc = nb + j * 16 + col;
    float s = g[oc] * rsqrtf(var[oc] + 1e-5f);
    float mm = mu[oc], bb = be[oc];
#pragma unroll
    for (int i = 0; i < 2; ++i) {
      int mbase = i * 16 + rq * 4;
      if (mbase < 30) {
        float r0 = fmaxf((acc[i][j][0] - mm) * s + bb, 0.f);
        float r1 = fmaxf((acc[i][j][1] - mm) * s + bb, 0.f);
        float* op = &out[(size_t)(b * 256 + oc) * HW + h * WIMG + w0 + mbase];
        *(float2*)op = make_float2(r0, r1);
        if (mbase < 28) {
          float r2 = fmaxf((acc[i][j][2] - mm) * s + bb, 0.f);
          float r3 = fmaxf((acc[i][j][3] - mm) * s + bb, 0.f);
          *(float2*)(op + 2) = make_float2(r2, r3);
        }
      }
    }
  }
}

// ---------------------------------------------------------------------------
extern "C" void kernel_launch(void* const* d_in, const int* in_sizes, int n_in,
                              void* d_out, int out_size, void* d_ws, size_t ws_size,
                              hipStream_t stream) {
  const float* camera = (const float*)d_in[0];
  const float* lidar  = (const float*)d_in[1];
  const float* cam_w  = (const float*)d_in[2];
  const float* cam_g  = (const float*)d_in[3];
  const float* cam_b  = (const float*)d_in[4];
  const float* cam_m  = (const float*)d_in[5];
  const float* cam_v  = (const float*)d_in[6];
  const float* lid_w  = (const float*)d_in[7];
  const float* lid_g  = (const float*)d_in[8];
  const float* lid_b  = (const float*)d_in[9];
  const float* lid_m  = (const float*)d_in[10];
  const float* lid_v  = (const float*)d_in[11];
  const float* ipw    = (const float*)d_in[12];
  const float* ipb    = (const float*)d_in[13];
  const float* opw    = (const float*)d_in[14];
  const float* opb    = (const float*)d_in[15];
  const float* ocw    = (const float*)d_in[16];
  const float* ocg    = (const float*)d_in[17];
  const float* ocb    = (const float*)d_in[18];
  const float* ocm    = (const float*)d_in[19];
  const float* ocv    = (const float*)d_in[20];

  __hip_bfloat16* ws = (__hip_bfloat16*)d_ws;
  const size_t NP = (size_t)2 * PSTRIDE * 128;
  __hip_bfloat16* cam_bf = ws;                    // aliased by fb later
  __hip_bfloat16* lid_bf = ws + NP;
  __hip_bfloat16* qc     = ws + 2 * NP;           // q, then ctx (in-place)
  __hip_bfloat16* kvb    = ws + 3 * NP;           // [p][256], 2*NP elements
  __hip_bfloat16* wipb   = ws + 5 * NP;           // 384*128
  __hip_bfloat16* wob    = wipb + 384 * 128;      // 128*128
  __hip_bfloat16* wcb    = wob + 128 * 128;       // 256*9*128
  __hip_bfloat16* wcamb  = wcb + 256 * 9 * 128;   // 128*128 (Kpad=128)
  __hip_bfloat16* wlidb  = wcamb + 128 * 128;     // 128*256
  __hip_bfloat16* fbbuf  = cam_bf;

  dim3 blk(256);
  // weight prep
  hipLaunchKernelGGL(k_cast, dim3(192), blk, 0, stream, ipw, wipb, 384 * 128);
  hipLaunchKernelGGL(k_cast, dim3(64), blk, 0, stream, opw, wob, 128 * 128);
  hipLaunchKernelGGL(k_prepw, dim3(1152), blk, 0, stream, ocw, wcb);
  hipLaunchKernelGGL(k_prepproj, dim3(64), blk, 0, stream, cam_w, wcamb, 80, 128);
  hipLaunchKernelGGL(k_prepproj, dim3(128), blk, 0, stream, lid_w, wlidb, 256, 256);
  // projections -> pixel-major bf16 (MFMA implicit GEMM)
  dim3 gproj(254, 1, 2);
  hipLaunchKernelGGL(k_proj_mfma, gproj, blk, 0, stream,
                     camera, wcamb, cam_g, cam_b, cam_m, cam_v, cam_bf, 80, 128);
  hipLaunchKernelGGL(k_proj_mfma, gproj, blk, 0, stream,
                     lidar, wlidb, lid_g, lid_b, lid_m, lid_v, lid_bf, 256, 256);
  // qkv GEMMs
  hipLaunchKernelGGL(k_gemm_bias, dim3(254, 1, 2), blk, 0, stream,
                     lid_bf, wipb, ipb, qc, 128, 128);
  hipLaunchKernelGGL(k_gemm_bias, dim3(254, 2, 2), blk, 0, stream,
                     cam_bf, wipb + 128 * 128, ipb + 128, kvb, 128, 256);
  // attention (qc -> qc in place)
  hipLaunchKernelGGL(k_attn_mfma, dim3(288, 8), blk, 0, stream, qc, kvb, qc);
  // zero padded fb (aliases cam_bf, dead after kv gemm)
  int n16 = (int)((2 * FBSZ * 2) / 16);
  hipLaunchKernelGGL(k_zero, dim3((n16 + 255) / 256), blk, 0, stream, (uint4*)fbbuf, n16);
  // out-proj + residual -> fb
  hipLaunchKernelGGL(k_outproj_mfma, dim3(254, 1, 2), blk, 0, stream,
                     qc, wob, opb, lid_bf, fbbuf);
  // conv + BN + ReLU
  hipLaunchKernelGGL(k_conv_mfma, dim3(1080, 1, 2), blk, 0, stream,
                     fbbuf, wcb, ocg, ocb, ocm, ocv, (float*)d_out);
}

// Round 8
// 368.596 us; speedup vs baseline: 7.6669x; 1.0860x over previous
//
#include <hip/hip_runtime.h>
#include <hip/hip_bf16.h>
#include <cmath>

#define HW      32400
#define WIMG    180
#define DD      128
#define NHEADS  8
#define DHEAD   16
#define LTOK    225
#define PSTRIDE 64928            // 32400 + slack per batch
#define FBROW   188
#define FBH     182
#define FBSZ    ((size_t)FBH * FBROW * 128)   // padded pixel-major conv input per batch

typedef __attribute__((ext_vector_type(8))) short bf16x8;
typedef __attribute__((ext_vector_type(4))) float f32x4;

union U16B { uint4 u; int4 i; bf16x8 v; };

__device__ __forceinline__ bf16x8 ldfrag(const __hip_bfloat16* p, int ld, int lane) {
  // fragment for mfma_f32_16x16x32_bf16: row = lane&15 (stride ld), k = (lane>>4)*8..+7 contiguous
  return *(const bf16x8*)(p + (size_t)(lane & 15) * ld + ((lane >> 4) << 3));
}

__device__ __forceinline__ float bf2f(unsigned int u) {
  return __uint_as_float(u << 16);
}

__device__ __forceinline__ unsigned short f2bf(float x) {
  unsigned int b = __float_as_uint(x);
  return (unsigned short)((b + 0x7fffu + ((b >> 16) & 1u)) >> 16);
}

__device__ __forceinline__ void gload16(const void* g, void* l) {
  __builtin_amdgcn_global_load_lds(
      (const __attribute__((address_space(1))) unsigned int*)g,
      (__attribute__((address_space(3))) unsigned int*)l, 16, 0, 0);
}

// ---------------------------------------------------------------------------
// weight prep
// ---------------------------------------------------------------------------
__global__ void k_cast(const float* __restrict__ in, __hip_bfloat16* __restrict__ out, int n) {
  int i = blockIdx.x * 256 + threadIdx.x;
  if (i < n) out[i] = __float2bfloat16(in[i]);
}

__global__ void k_prepproj(const float* __restrict__ w, __hip_bfloat16* __restrict__ wb,
                           int C, int Kpad) {
  int i = blockIdx.x * 256 + threadIdx.x;
  if (i >= 128 * Kpad) return;
  int d = i / Kpad, c = i % Kpad;
  wb[i] = (c < C) ? __float2bfloat16(w[d * C + c]) : __float2bfloat16(0.f);
}

__global__ void k_prepw(const float* __restrict__ cw, __hip_bfloat16* __restrict__ wcb) {
  int i = blockIdx.x * 256 + threadIdx.x;
  if (i < 256 * 9 * 128) {
    int oc = i / 1152, t = (i % 1152) / 128, ic = i % 128;
    wcb[i] = __float2bfloat16(cw[(size_t)(oc * 128 + ic) * 9 + t]);
  }
}

__global__ void k_zero(uint4* __restrict__ p, int n16) {
  int i = blockIdx.x * 256 + threadIdx.x;
  if (i < n16) p[i] = make_uint4(0u, 0u, 0u, 0u);
}

// ---------------------------------------------------------------------------
// 1) 1x1 conv + BN + ReLU as implicit MFMA GEMM (unchanged)
// ---------------------------------------------------------------------------
__global__ void __launch_bounds__(256) k_proj_mfma(
    const float* __restrict__ in, const __hip_bfloat16* __restrict__ wb,
    const float* __restrict__ g, const float* __restrict__ be,
    const float* __restrict__ mu, const float* __restrict__ var,
    __hip_bfloat16* __restrict__ outp, int C, int Kpad) {
  __shared__ __align__(16) __hip_bfloat16 sa[128 * 64];
  int m0 = blockIdx.x * 128;
  int b = blockIdx.z;
  int tid = threadIdx.x, lane = tid & 63, wid = tid >> 6;
  int wm = (wid >> 1) * 64, wn = (wid & 1) * 64;
  const float* inb = in + (size_t)b * C * HW;
  int sp = (tid >> 1) & 127;
  int sc4 = (tid & 1) * 4;
  int gp = m0 + sp;
  bool pok = gp < HW;
  f32x4 acc[4][4] = {};
  for (int kc = 0; kc < Kpad; kc += 64) {
    __syncthreads();
#pragma unroll
    for (int it = 0; it < 8; ++it) {
      int lc = sc4 + it * 8;
      int c = kc + lc;
      unsigned short u[4];
#pragma unroll
      for (int j = 0; j < 4; ++j) {
        float x = (pok && (c + j) < C) ? inb[(size_t)(c + j) * HW + gp] : 0.f;
        u[j] = f2bf(x);
      }
      int blk = (lc >> 3) ^ (sp & 7);
      char* dst = (char*)sa + sp * 128 + blk * 16 + (lc & 7) * 2;
      *(uint2*)dst = make_uint2(((unsigned)u[1] << 16) | u[0],
                                ((unsigned)u[3] << 16) | u[2]);
    }
    __syncthreads();
#pragma unroll
    for (int ks = 0; ks < 2; ++ks) {
      bf16x8 af[4], bfr[4];
#pragma unroll
      for (int i = 0; i < 4; ++i) {
        int pr = wm + i * 16 + (lane & 15);
        int blk = ((ks * 4 + (lane >> 4)) ^ (pr & 7));
        af[i] = *(const bf16x8*)((const char*)sa + pr * 128 + blk * 16);
      }
#pragma unroll
      for (int j = 0; j < 4; ++j)
        bfr[j] = ldfrag(wb + (size_t)(wn + j * 16) * Kpad + kc + ks * 32, Kpad, lane);
#pragma unroll
      for (int i = 0; i < 4; ++i)
#pragma unroll
        for (int j = 0; j < 4; ++j)
          acc[i][j] = __builtin_amdgcn_mfma_f32_16x16x32_bf16(af[i], bfr[j], acc[i][j], 0, 0, 0);
    }
  }
  int col = lane & 15, rq = lane >> 4;
  __hip_bfloat16* ob = outp + (size_t)b * PSTRIDE * 128;
#pragma unroll
  for (int j = 0; j < 4; ++j) {
    int d = wn + j * 16 + col;
    float s = g[d] * rsqrtf(var[d] + 1e-5f);
    float mm = mu[d], bb = be[d];
#pragma unroll
    for (int i = 0; i < 4; ++i) {
#pragma unroll
      for (int r = 0; r < 4; ++r) {
        int m = m0 + wm + i * 16 + rq * 4 + r;
        if (m < HW) {
          float y = (acc[i][j][r] - mm) * s + bb;
          ob[(size_t)m * 128 + d] = __float2bfloat16(fmaxf(y, 0.f));
        }
      }
    }
  }
}

// ---------------------------------------------------------------------------
// 2) MFMA GEMM with bias (unchanged)
// ---------------------------------------------------------------------------
__global__ void __launch_bounds__(256) k_gemm_bias(
    const __hip_bfloat16* __restrict__ A, const __hip_bfloat16* __restrict__ B,
    const float* __restrict__ bias, __hip_bfloat16* __restrict__ out,
    int K, int ldout) {
  int m0 = blockIdx.x * 128, n0 = blockIdx.y * 128, b = blockIdx.z;
  int lane = threadIdx.x & 63, wid = threadIdx.x >> 6;
  int wm = (wid >> 1) * 64, wn = (wid & 1) * 64;
  const __hip_bfloat16* Ab = A + (size_t)b * PSTRIDE * K;
  f32x4 acc[4][4] = {};
  for (int kc = 0; kc < K; kc += 32) {
    bf16x8 af[4], bfr[4];
#pragma unroll
    for (int i = 0; i < 4; ++i)
      af[i] = ldfrag(Ab + (size_t)(m0 + wm + i * 16) * K + kc, K, lane);
#pragma unroll
    for (int j = 0; j < 4; ++j)
      bfr[j] = ldfrag(B + (size_t)(n0 + wn + j * 16) * K + kc, K, lane);
#pragma unroll
    for (int i = 0; i < 4; ++i)
#pragma unroll
      for (int j = 0; j < 4; ++j)
        acc[i][j] = __builtin_amdgcn_mfma_f32_16x16x32_bf16(af[i], bfr[j], acc[i][j], 0, 0, 0);
  }
  int col = lane & 15, rq = lane >> 4;
  __hip_bfloat16* ob = out + (size_t)b * PSTRIDE * ldout;
#pragma unroll
  for (int j = 0; j < 4; ++j) {
    int n = n0 + wn + j * 16 + col;
    float bs = bias[n];
#pragma unroll
    for (int i = 0; i < 4; ++i) {
#pragma unroll
      for (int r = 0; r < 4; ++r) {
        int m = m0 + wm + i * 16 + rq * 4 + r;
        if (m < HW) ob[(size_t)m * ldout + n] = __float2bfloat16(acc[i][j][r] + bs);
      }
    }
  }
}

// ---------------------------------------------------------------------------
// 3) MFMA flash attention per (bn, head) (unchanged from r6)
// ---------------------------------------------------------------------------
__global__ void __launch_bounds__(256) k_attn_mfma(
    const __hip_bfloat16* __restrict__ qc, const __hip_bfloat16* __restrict__ kvb,
    __hip_bfloat16* __restrict__ ctx) {
  __shared__ __align__(16) unsigned short ksh[240 * 32];  // [key][dh pad 32], swizzled
  __shared__ __align__(16) unsigned short vsh[16 * 248];  // V^T [d][key]
  __shared__ __align__(16) unsigned short psh[4 * 256];   // per-wave P^T[q][key16]
  int bn = blockIdx.x, hh = blockIdx.y;
  int b = bn / 144, rr = bn % 144, tby = rr / 12, tbx = rr % 12;
  int tid = threadIdx.x;
  int pbase = tby * 15 * WIMG + tbx * 15;
  const __hip_bfloat16* kvbase = kvb + (size_t)b * PSTRIDE * 256 + hh * 16;

  if (tid < 240) {
    int row = tid;
    unsigned short kv16[16];
#pragma unroll
    for (int j = 0; j < 16; ++j) kv16[j] = 0;
    unsigned short vv16[16];
#pragma unroll
    for (int j = 0; j < 16; ++j) vv16[j] = 0;
    if (row < LTOK) {
      int p = pbase + (row / 15) * WIMG + (row % 15);
      const uint4* kp = (const uint4*)(kvbase + (size_t)p * 256);
      uint4 k0 = kp[0], k1 = kp[1];
      uint4 v0 = kp[16], v1 = kp[17];
      unsigned kw[8] = {k0.x, k0.y, k0.z, k0.w, k1.x, k1.y, k1.z, k1.w};
      unsigned vw[8] = {v0.x, v0.y, v0.z, v0.w, v1.x, v1.y, v1.z, v1.w};
#pragma unroll
      for (int j = 0; j < 8; ++j) {
        kv16[2 * j]     = (unsigned short)(__float_as_uint(bf2f(kw[j] & 0xffffu) * 0.25f) >> 16);
        kv16[2 * j + 1] = (unsigned short)(__float_as_uint(bf2f(kw[j] >> 16) * 0.25f) >> 16);
        vv16[2 * j]     = (unsigned short)(vw[j] & 0xffffu);
        vv16[2 * j + 1] = (unsigned short)(vw[j] >> 16);
      }
    }
    char* kbase = (char*)ksh + row * 64;
    uint4 zz = make_uint4(0, 0, 0, 0);
    *(uint4*)(kbase + ((0 ^ (row & 3)) << 4)) = ((uint4*)kv16)[0];
    *(uint4*)(kbase + ((1 ^ (row & 3)) << 4)) = ((uint4*)kv16)[1];
    *(uint4*)(kbase + ((2 ^ (row & 3)) << 4)) = zz;
    *(uint4*)(kbase + ((3 ^ (row & 3)) << 4)) = zz;
#pragma unroll
    for (int d = 0; d < 16; ++d) vsh[d * 248 + row] = vv16[d];
  }
  __syncthreads();

  int lane = tid & 63, wid = tid >> 6;
  int g = lane >> 4, q15 = lane & 15;
  int wq0 = wid * 64;
  char* pw_base = (char*)psh + wid * 512;

  bf16x8 qf[4];
#pragma unroll
  for (int i = 0; i < 4; ++i) {
    int q = wq0 + i * 16 + q15;
    int qq = q < LTOK ? q : 0;
    int p = pbase + (qq / 15) * WIMG + (qq % 15);
    U16B u; u.u = make_uint4(0, 0, 0, 0);
    if (g < 2) u.u = *(const uint4*)(qc + ((size_t)b * PSTRIDE + p) * 128 + hh * 16 + g * 8);
    qf[i] = u.v;
  }

  float m_[4], ls[4];
  f32x4 oac[4] = {};
#pragma unroll
  for (int i = 0; i < 4; ++i) { m_[i] = -3.0e38f; ls[i] = 0.f; }
  const f32x4 zacc = {};

  for (int ck = 0; ck < 15; ++ck) {
    int rowb = ck * 16 + q15;
    bf16x8 kf = *(const bf16x8*)((const char*)ksh + rowb * 64 + ((g ^ (rowb & 3)) << 4));
    U16B vu; vu.u = make_uint4(0, 0, 0, 0);
    if (g < 2) vu.u = *(const uint4*)((const char*)vsh + (q15 * 248 + ck * 16 + g * 8) * 2);
    bf16x8 vf = vu.v;
#pragma unroll
    for (int i = 0; i < 4; ++i) {
      f32x4 st = __builtin_amdgcn_mfma_f32_16x16x32_bf16(kf, qf[i], zacc, 0, 0, 0);
      float s0 = st[0], s1 = st[1], s2 = st[2], s3 = st[3];
      if (ck == 14) {
        s0 = (g == 0) ? s0 : -3.0e38f;
        s1 = -3.0e38f; s2 = -3.0e38f; s3 = -3.0e38f;
      }
      float cm = fmaxf(fmaxf(s0, s1), fmaxf(s2, s3));
      cm = fmaxf(cm, __shfl_xor(cm, 16));
      cm = fmaxf(cm, __shfl_xor(cm, 32));
      float mn = fmaxf(m_[i], cm);
      float corr = __expf(m_[i] - mn);
      float p0 = __expf(s0 - mn), p1 = __expf(s1 - mn);
      float p2 = __expf(s2 - mn), p3 = __expf(s3 - mn);
      float ps = (p0 + p1) + (p2 + p3);
      ps += __shfl_xor(ps, 16);
      ps += __shfl_xor(ps, 32);
      ls[i] = ls[i] * corr + ps;
      m_[i] = mn;
      unsigned w0 = (unsigned)f2bf(p0) | ((unsigned)f2bf(p1) << 16);
      unsigned w1 = (unsigned)f2bf(p2) | ((unsigned)f2bf(p3) << 16);
      *(uint2*)(pw_base + q15 * 32 + g * 8) = make_uint2(w0, w1);
      U16B pu; pu.u = make_uint4(0, 0, 0, 0);
      if (g < 2) pu.u = *(const uint4*)(pw_base + q15 * 32 + g * 16);
      f32x4 oc = oac[i];
      oc[0] *= corr; oc[1] *= corr; oc[2] *= corr; oc[3] *= corr;
      oac[i] = __builtin_amdgcn_mfma_f32_16x16x32_bf16(vf, pu.v, oc, 0, 0, 0);
    }
  }

  __hip_bfloat16* cb = ctx + (size_t)b * PSTRIDE * 128 + hh * 16;
#pragma unroll
  for (int i = 0; i < 4; ++i) {
    float inv = 1.f / ls[i];
    int qo = wq0 + i * 16 + q15;
    if (qo < LTOK) {
      unsigned lo = (unsigned)f2bf(oac[i][0] * inv) | ((unsigned)f2bf(oac[i][1] * inv) << 16);
      unsigned hi = (unsigned)f2bf(oac[i][2] * inv) | ((unsigned)f2bf(oac[i][3] * inv) << 16);
      int p = pbase + (qo / 15) * WIMG + (qo % 15);
      *(uint2*)(cb + (size_t)p * 128 + g * 4) = make_uint2(lo, hi);
    }
  }
}

// ---------------------------------------------------------------------------
// 4) out-proj MFMA GEMM + bias + residual -> padded fb bf16 (unchanged)
// ---------------------------------------------------------------------------
__global__ void __launch_bounds__(256) k_outproj_mfma(
    const __hip_bfloat16* __restrict__ ctx, const __hip_bfloat16* __restrict__ wob,
    const float* __restrict__ opb, const __hip_bfloat16* __restrict__ lidb,
    __hip_bfloat16* __restrict__ fb) {
  int m0 = blockIdx.x * 128, b = blockIdx.z;
  int lane = threadIdx.x & 63, wid = threadIdx.x >> 6;
  int wm = (wid >> 1) * 64, wn = (wid & 1) * 64;
  const __hip_bfloat16* Ab = ctx + (size_t)b * PSTRIDE * 128;
  f32x4 acc[4][4] = {};
  for (int kc = 0; kc < 128; kc += 32) {
    bf16x8 af[4], bfr[4];
#pragma unroll
    for (int i = 0; i < 4; ++i)
      af[i] = ldfrag(Ab + (size_t)(m0 + wm + i * 16) * 128 + kc, 128, lane);
#pragma unroll
    for (int j = 0; j < 4; ++j)
      bfr[j] = ldfrag(wob + (size_t)(wn + j * 16) * 128 + kc, 128, lane);
#pragma unroll
    for (int i = 0; i < 4; ++i)
#pragma unroll
      for (int j = 0; j < 4; ++j)
        acc[i][j] = __builtin_amdgcn_mfma_f32_16x16x32_bf16(af[i], bfr[j], acc[i][j], 0, 0, 0);
  }
  int col = lane & 15, rq = lane >> 4;
  const __hip_bfloat16* lb = lidb + (size_t)b * PSTRIDE * 128;
  __hip_bfloat16* fbp = fb + (size_t)b * FBSZ;
#pragma unroll
  for (int j = 0; j < 4; ++j) {
    int n = wn + j * 16 + col;
    float bs = opb[n];
#pragma unroll
    for (int i = 0; i < 4; ++i) {
#pragma unroll
      for (int r = 0; r < 4; ++r) {
        int m = m0 + wm + i * 16 + rq * 4 + r;
        if (m < HW) {
          float v = acc[i][j][r] + bs + __bfloat162float(lb[(size_t)m * 128 + n]);
          int hhh = m / WIMG, www = m % WIMG;
          fbp[((size_t)(hhh + 1) * FBROW + (www + 1)) * 128 + n] = __float2bfloat16(v);
        }
      }
    }
  }
}

// ---------------------------------------------------------------------------
// 5) 3x3 conv 128->256 + BN + ReLU, LDS-pipelined implicit GEMM.
//    Block: 60 px (one row) x 128 oc. A halo staged once (K-major, 46.5 KB).
//    B streamed per k-step (tap,chunk32) via global_load_lds double-buffer.
// ---------------------------------------------------------------------------
__global__ void __launch_bounds__(256) k_conv_mfma(
    const __hip_bfloat16* __restrict__ fb, const __hip_bfloat16* __restrict__ wcb,
    const float* __restrict__ g, const float* __restrict__ be,
    const float* __restrict__ mu, const float* __restrict__ var,
    float* __restrict__ out) {
  __shared__ __align__(16) uint4 smem[2976 + 1024];   // A: 2976 slots, B: 2x512 slots
  uint4* Asm = smem;
  uint4* Bsm = smem + 2976;
  int bx = blockIdx.x;                 // 0..1079: row*6 + strip*2 + ocg
  int h = bx / 6, rem = bx % 6;
  int strip = rem >> 1, ocg = rem & 1;
  int w0 = strip * 60;
  int ocbase = ocg * 128;
  int b = blockIdx.z;
  int tid = threadIdx.x, lane = tid & 63, wid = tid >> 6;
  int q15 = lane & 15, kg = lane >> 4;
  int wpx = (wid & 1) * 32;            // pixel half
  int woc = (wid >> 1) * 64;           // oc half (within block's 128)
  const __hip_bfloat16* fbb = fb + (size_t)b * FBSZ;
  const __hip_bfloat16* wsl = wcb + (size_t)ocbase * 1152;

  // ---- prologue: stage B(step 0) async, then A halo (3 rows x 62 px, K-major) ----
#pragma unroll
  for (int it = 0; it < 2; ++it) {
    int sidx = it * 256 + tid;
    int skg = sidx >> 7, soc = sidx & 127;
    gload16(wsl + (size_t)soc * 1152 + skg * 8, (char*)Bsm + sidx * 16);
  }
#pragma unroll
  for (int it = 0; it < 12; ++it) {
    int slot = it * 256 + tid;
    if (slot < 2976) {
      int px = slot % 62;
      int rowk = slot / 62;            // dy*16 + kgrp
      int dy = rowk >> 4, kgrp = rowk & 15;
      Asm[slot] = *(const uint4*)(fbb + ((size_t)(h + dy) * FBROW + (w0 + px)) * 128 + kgrp * 8);
    }
  }
  __syncthreads();   // drains vmcnt (global_load_lds) + lgkm (ds_writes)

  f32x4 acc[2][4] = {};
  // ---- main loop: 36 k-steps (t = tap*4 + chunk) ----
  for (int t = 0; t < 36; ++t) {
    int cur = t & 1;
    if (t + 1 < 36) {
      int tn = t + 1;
      int tapn = tn >> 2, chn = tn & 3;
      const __hip_bfloat16* bsrc = wsl + tapn * 128 + chn * 32;
      char* bdst = (char*)(Bsm + (tn & 1) * 512);
#pragma unroll
      for (int it = 0; it < 2; ++it) {
        int sidx = it * 256 + tid;
        int skg = sidx >> 7, soc = sidx & 127;
        gload16(bsrc + (size_t)soc * 1152 + skg * 8, bdst + sidx * 16);
      }
    }
    int tap = t >> 2, chunk = t & 3;
    int dy = tap / 3, dx = tap % 3;
    int rowk = (dy * 16 + chunk * 4 + kg) * 62;
    bf16x8 af[2], bfr[4];
#pragma unroll
    for (int i = 0; i < 2; ++i)
      af[i] = *(const bf16x8*)&Asm[rowk + wpx + i * 16 + q15 + dx];
#pragma unroll
    for (int j = 0; j < 4; ++j)
      bfr[j] = *(const bf16x8*)&Bsm[cur * 512 + kg * 128 + woc + j * 16 + q15];
#pragma unroll
    for (int i = 0; i < 2; ++i)
#pragma unroll
      for (int j = 0; j < 4; ++j)
        acc[i][j] = __builtin_amdgcn_mfma_f32_16x16x32_bf16(af[i], bfr[j], acc[i][j], 0, 0, 0);
    __syncthreads();   // implicit vmcnt(0): next-step B staged; buffers safe to swap
  }

  // ---- epilogue: BN + ReLU + store (D: col=oc (q15), row=px (kg*4+r)) ----
#pragma unroll
  for (int j = 0; j < 4; ++j) {
    int oc = ocbase + woc + j * 16 + q15;
    float s = g[oc] * rsqrtf(var[oc] + 1e-5f);
    float mm = mu[oc], bb = be[oc];
#pragma unroll
    for (int i = 0; i < 2; ++i) {
      int pxb = wpx + i * 16 + kg * 4;
      if (pxb < 60) {
        float4 o4;
        o4.x = fmaxf((acc[i][j][0] - mm) * s + bb, 0.f);
        o4.y = fmaxf((acc[i][j][1] - mm) * s + bb, 0.f);
        o4.z = fmaxf((acc[i][j][2] - mm) * s + bb, 0.f);
        o4.w = fmaxf((acc[i][j][3] - mm) * s + bb, 0.f);
        *(float4*)(&out[(size_t)(b * 256 + oc) * HW + h * WIMG + w0 + pxb]) = o4;
      }
    }
  }
}

// ---------------------------------------------------------------------------
extern "C" void kernel_launch(void* const* d_in, const int* in_sizes, int n_in,
                              void* d_out, int out_size, void* d_ws, size_t ws_size,
                              hipStream_t stream) {
  const float* camera = (const float*)d_in[0];
  const float* lidar  = (const float*)d_in[1];
  const float* cam_w  = (const float*)d_in[2];
  const float* cam_g  = (const float*)d_in[3];
  const float* cam_b  = (const float*)d_in[4];
  const float* cam_m  = (const float*)d_in[5];
  const float* cam_v  = (const float*)d_in[6];
  const float* lid_w  = (const float*)d_in[7];
  const float* lid_g  = (const float*)d_in[8];
  const float* lid_b  = (const float*)d_in[9];
  const float* lid_m  = (const float*)d_in[10];
  const float* lid_v  = (const float*)d_in[11];
  const float* ipw    = (const float*)d_in[12];
  const float* ipb    = (const float*)d_in[13];
  const float* opw    = (const float*)d_in[14];
  const float* opb    = (const float*)d_in[15];
  const float* ocw    = (const float*)d_in[16];
  const float* ocg    = (const float*)d_in[17];
  const float* ocb    = (const float*)d_in[18];
  const float* ocm    = (const float*)d_in[19];
  const float* ocv    = (const float*)d_in[20];

  __hip_bfloat16* ws = (__hip_bfloat16*)d_ws;
  const size_t NP = (size_t)2 * PSTRIDE * 128;
  __hip_bfloat16* cam_bf = ws;                    // aliased by fb later
  __hip_bfloat16* lid_bf = ws + NP;
  __hip_bfloat16* qc     = ws + 2 * NP;           // q, then ctx (in-place)
  __hip_bfloat16* kvb    = ws + 3 * NP;           // [p][256], 2*NP elements
  __hip_bfloat16* wipb   = ws + 5 * NP;           // 384*128
  __hip_bfloat16* wob    = wipb + 384 * 128;      // 128*128
  __hip_bfloat16* wcb    = wob + 128 * 128;       // 256*9*128
  __hip_bfloat16* wcamb  = wcb + 256 * 9 * 128;   // 128*128 (Kpad=128)
  __hip_bfloat16* wlidb  = wcamb + 128 * 128;     // 128*256
  __hip_bfloat16* fbbuf  = cam_bf;

  dim3 blk(256);
  // weight prep
  hipLaunchKernelGGL(k_cast, dim3(192), blk, 0, stream, ipw, wipb, 384 * 128);
  hipLaunchKernelGGL(k_cast, dim3(64), blk, 0, stream, opw, wob, 128 * 128);
  hipLaunchKernelGGL(k_prepw, dim3(1152), blk, 0, stream, ocw, wcb);
  hipLaunchKernelGGL(k_prepproj, dim3(64), blk, 0, stream, cam_w, wcamb, 80, 128);
  hipLaunchKernelGGL(k_prepproj, dim3(128), blk, 0, stream, lid_w, wlidb, 256, 256);
  // projections -> pixel-major bf16 (MFMA implicit GEMM)
  dim3 gproj(254, 1, 2);
  hipLaunchKernelGGL(k_proj_mfma, gproj, blk, 0, stream,
                     camera, wcamb, cam_g, cam_b, cam_m, cam_v, cam_bf, 80, 128);
  hipLaunchKernelGGL(k_proj_mfma, gproj, blk, 0, stream,
                     lidar, wlidb, lid_g, lid_b, lid_m, lid_v, lid_bf, 256, 256);
  // qkv GEMMs
  hipLaunchKernelGGL(k_gemm_bias, dim3(254, 1, 2), blk, 0, stream,
                     lid_bf, wipb, ipb, qc, 128, 128);
  hipLaunchKernelGGL(k_gemm_bias, dim3(254, 2, 2), blk, 0, stream,
                     cam_bf, wipb + 128 * 128, ipb + 128, kvb, 128, 256);
  // attention (qc -> qc in place)
  hipLaunchKernelGGL(k_attn_mfma, dim3(288, 8), blk, 0, stream, qc, kvb, qc);
  // zero padded fb (aliases cam_bf, dead after kv gemm)
  int n16 = (int)((2 * FBSZ * 2) / 16);
  hipLaunchKernelGGL(k_zero, dim3((n16 + 255) / 256), blk, 0, stream, (uint4*)fbbuf, n16);
  // out-proj + residual -> fb
  hipLaunchKernelGGL(k_outproj_mfma, dim3(254, 1, 2), blk, 0, stream,
                     qc, wob, opb, lid_bf, fbbuf);
  // conv + BN + ReLU
  hipLaunchKernelGGL(k_conv_mfma, dim3(1080, 1, 2), blk, 0, stream,
                     fbbuf, wcb, ocg, ocb, ocm, ocv, (float*)d_out);
}

// Round 9
// 310.114 us; speedup vs baseline: 9.1128x; 1.1886x over previous
//
#include <hip/hip_runtime.h>
#include <hip/hip_bf16.h>
#include <cmath>

#define HW      32400
#define WIMG    180
#define DD      128
#define NHEADS  8
#define DHEAD   16
#define LTOK    225
#define PSTRIDE 64928            // 32400 + slack per batch
#define FBROW   188
#define FBH     182
#define FBSZ    ((size_t)FBH * FBROW * 128)   // padded pixel-major conv input per batch

typedef __attribute__((ext_vector_type(8))) short bf16x8;
typedef __attribute__((ext_vector_type(4))) float f32x4;

union U16B { uint4 u; int4 i; bf16x8 v; };

__device__ __forceinline__ bf16x8 ldfrag(const __hip_bfloat16* p, int ld, int lane) {
  // fragment for mfma_f32_16x16x32_bf16: row = lane&15 (stride ld), k = (lane>>4)*8..+7 contiguous
  return *(const bf16x8*)(p + (size_t)(lane & 15) * ld + ((lane >> 4) << 3));
}

__device__ __forceinline__ float bf2f(unsigned int u) {
  return __uint_as_float(u << 16);
}

__device__ __forceinline__ unsigned short f2bf(float x) {
  unsigned int b = __float_as_uint(x);
  return (unsigned short)((b + 0x7fffu + ((b >> 16) & 1u)) >> 16);
}

// ---------------------------------------------------------------------------
// weight prep
// ---------------------------------------------------------------------------
__global__ void k_cast(const float* __restrict__ in, __hip_bfloat16* __restrict__ out, int n) {
  int i = blockIdx.x * 256 + threadIdx.x;
  if (i < n) out[i] = __float2bfloat16(in[i]);
}

__global__ void k_prepproj(const float* __restrict__ w, __hip_bfloat16* __restrict__ wb,
                           int C, int Kpad) {
  int i = blockIdx.x * 256 + threadIdx.x;
  if (i >= 128 * Kpad) return;
  int d = i / Kpad, c = i % Kpad;
  wb[i] = (c < C) ? __float2bfloat16(w[d * C + c]) : __float2bfloat16(0.f);
}

// conv weights -> frag-major: [oc16(16)][tap(9)][chunk(4)][lane(64)][e(8)]
//   oc = oc16*16 + (lane&15), ic = chunk*32 + (lane>>4)*8 + e
__global__ void k_prepw2(const float* __restrict__ cw, __hip_bfloat16* __restrict__ wcb) {
  int i = blockIdx.x * 256 + threadIdx.x;
  if (i >= 294912) return;
  int oc16  = i / 18432;
  int r0    = i % 18432;
  int tap   = r0 / 2048;
  int r1    = r0 % 2048;
  int chunk = r1 / 512;
  int r2    = r1 % 512;
  int lane  = r2 / 8;
  int e     = r2 % 8;
  int oc = oc16 * 16 + (lane & 15);
  int ic = chunk * 32 + (lane >> 4) * 8 + e;
  wcb[i] = __float2bfloat16(cw[(size_t)(oc * 128 + ic) * 9 + tap]);
}

__global__ void k_zero(uint4* __restrict__ p, int n16) {
  int i = blockIdx.x * 256 + threadIdx.x;
  if (i < n16) p[i] = make_uint4(0u, 0u, 0u, 0u);
}

// ---------------------------------------------------------------------------
// 1) 1x1 conv + BN + ReLU as implicit MFMA GEMM (unchanged)
// ---------------------------------------------------------------------------
__global__ void __launch_bounds__(256) k_proj_mfma(
    const float* __restrict__ in, const __hip_bfloat16* __restrict__ wb,
    const float* __restrict__ g, const float* __restrict__ be,
    const float* __restrict__ mu, const float* __restrict__ var,
    __hip_bfloat16* __restrict__ outp, int C, int Kpad) {
  __shared__ __align__(16) __hip_bfloat16 sa[128 * 64];
  int m0 = blockIdx.x * 128;
  int b = blockIdx.z;
  int tid = threadIdx.x, lane = tid & 63, wid = tid >> 6;
  int wm = (wid >> 1) * 64, wn = (wid & 1) * 64;
  const float* inb = in + (size_t)b * C * HW;
  int sp = (tid >> 1) & 127;
  int sc4 = (tid & 1) * 4;
  int gp = m0 + sp;
  bool pok = gp < HW;
  f32x4 acc[4][4] = {};
  for (int kc = 0; kc < Kpad; kc += 64) {
    __syncthreads();
#pragma unroll
    for (int it = 0; it < 8; ++it) {
      int lc = sc4 + it * 8;
      int c = kc + lc;
      unsigned short u[4];
#pragma unroll
      for (int j = 0; j < 4; ++j) {
        float x = (pok && (c + j) < C) ? inb[(size_t)(c + j) * HW + gp] : 0.f;
        u[j] = f2bf(x);
      }
      int blk = (lc >> 3) ^ (sp & 7);
      char* dst = (char*)sa + sp * 128 + blk * 16 + (lc & 7) * 2;
      *(uint2*)dst = make_uint2(((unsigned)u[1] << 16) | u[0],
                                ((unsigned)u[3] << 16) | u[2]);
    }
    __syncthreads();
#pragma unroll
    for (int ks = 0; ks < 2; ++ks) {
      bf16x8 af[4], bfr[4];
#pragma unroll
      for (int i = 0; i < 4; ++i) {
        int pr = wm + i * 16 + (lane & 15);
        int blk = ((ks * 4 + (lane >> 4)) ^ (pr & 7));
        af[i] = *(const bf16x8*)((const char*)sa + pr * 128 + blk * 16);
      }
#pragma unroll
      for (int j = 0; j < 4; ++j)
        bfr[j] = ldfrag(wb + (size_t)(wn + j * 16) * Kpad + kc + ks * 32, Kpad, lane);
#pragma unroll
      for (int i = 0; i < 4; ++i)
#pragma unroll
        for (int j = 0; j < 4; ++j)
          acc[i][j] = __builtin_amdgcn_mfma_f32_16x16x32_bf16(af[i], bfr[j], acc[i][j], 0, 0, 0);
    }
  }
  int col = lane & 15, rq = lane >> 4;
  __hip_bfloat16* ob = outp + (size_t)b * PSTRIDE * 128;
#pragma unroll
  for (int j = 0; j < 4; ++j) {
    int d = wn + j * 16 + col;
    float s = g[d] * rsqrtf(var[d] + 1e-5f);
    float mm = mu[d], bb = be[d];
#pragma unroll
    for (int i = 0; i < 4; ++i) {
#pragma unroll
      for (int r = 0; r < 4; ++r) {
        int m = m0 + wm + i * 16 + rq * 4 + r;
        if (m < HW) {
          float y = (acc[i][j][r] - mm) * s + bb;
          ob[(size_t)m * 128 + d] = __float2bfloat16(fmaxf(y, 0.f));
        }
      }
    }
  }
}

// ---------------------------------------------------------------------------
// 2) MFMA GEMM with bias (unchanged)
// ---------------------------------------------------------------------------
__global__ void __launch_bounds__(256) k_gemm_bias(
    const __hip_bfloat16* __restrict__ A, const __hip_bfloat16* __restrict__ B,
    const float* __restrict__ bias, __hip_bfloat16* __restrict__ out,
    int K, int ldout) {
  int m0 = blockIdx.x * 128, n0 = blockIdx.y * 128, b = blockIdx.z;
  int lane = threadIdx.x & 63, wid = threadIdx.x >> 6;
  int wm = (wid >> 1) * 64, wn = (wid & 1) * 64;
  const __hip_bfloat16* Ab = A + (size_t)b * PSTRIDE * K;
  f32x4 acc[4][4] = {};
  for (int kc = 0; kc < K; kc += 32) {
    bf16x8 af[4], bfr[4];
#pragma unroll
    for (int i = 0; i < 4; ++i)
      af[i] = ldfrag(Ab + (size_t)(m0 + wm + i * 16) * K + kc, K, lane);
#pragma unroll
    for (int j = 0; j < 4; ++j)
      bfr[j] = ldfrag(B + (size_t)(n0 + wn + j * 16) * K + kc, K, lane);
#pragma unroll
    for (int i = 0; i < 4; ++i)
#pragma unroll
      for (int j = 0; j < 4; ++j)
        acc[i][j] = __builtin_amdgcn_mfma_f32_16x16x32_bf16(af[i], bfr[j], acc[i][j], 0, 0, 0);
  }
  int col = lane & 15, rq = lane >> 4;
  __hip_bfloat16* ob = out + (size_t)b * PSTRIDE * ldout;
#pragma unroll
  for (int j = 0; j < 4; ++j) {
    int n = n0 + wn + j * 16 + col;
    float bs = bias[n];
#pragma unroll
    for (int i = 0; i < 4; ++i) {
#pragma unroll
      for (int r = 0; r < 4; ++r) {
        int m = m0 + wm + i * 16 + rq * 4 + r;
        if (m < HW) ob[(size_t)m * ldout + n] = __float2bfloat16(acc[i][j][r] + bs);
      }
    }
  }
}

// ---------------------------------------------------------------------------
// 3) MFMA flash attention per (bn, head) (unchanged)
// ---------------------------------------------------------------------------
__global__ void __launch_bounds__(256) k_attn_mfma(
    const __hip_bfloat16* __restrict__ qc, const __hip_bfloat16* __restrict__ kvb,
    __hip_bfloat16* __restrict__ ctx) {
  __shared__ __align__(16) unsigned short ksh[240 * 32];
  __shared__ __align__(16) unsigned short vsh[16 * 248];
  __shared__ __align__(16) unsigned short psh[4 * 256];
  int bn = blockIdx.x, hh = blockIdx.y;
  int b = bn / 144, rr = bn % 144, tby = rr / 12, tbx = rr % 12;
  int tid = threadIdx.x;
  int pbase = tby * 15 * WIMG + tbx * 15;
  const __hip_bfloat16* kvbase = kvb + (size_t)b * PSTRIDE * 256 + hh * 16;

  if (tid < 240) {
    int row = tid;
    unsigned short kv16[16];
#pragma unroll
    for (int j = 0; j < 16; ++j) kv16[j] = 0;
    unsigned short vv16[16];
#pragma unroll
    for (int j = 0; j < 16; ++j) vv16[j] = 0;
    if (row < LTOK) {
      int p = pbase + (row / 15) * WIMG + (row % 15);
      const uint4* kp = (const uint4*)(kvbase + (size_t)p * 256);
      uint4 k0 = kp[0], k1 = kp[1];
      uint4 v0 = kp[16], v1 = kp[17];
      unsigned kw[8] = {k0.x, k0.y, k0.z, k0.w, k1.x, k1.y, k1.z, k1.w};
      unsigned vw[8] = {v0.x, v0.y, v0.z, v0.w, v1.x, v1.y, v1.z, v1.w};
#pragma unroll
      for (int j = 0; j < 8; ++j) {
        kv16[2 * j]     = (unsigned short)(__float_as_uint(bf2f(kw[j] & 0xffffu) * 0.25f) >> 16);
        kv16[2 * j + 1] = (unsigned short)(__float_as_uint(bf2f(kw[j] >> 16) * 0.25f) >> 16);
        vv16[2 * j]     = (unsigned short)(vw[j] & 0xffffu);
        vv16[2 * j + 1] = (unsigned short)(vw[j] >> 16);
      }
    }
    char* kbase = (char*)ksh + row * 64;
    uint4 zz = make_uint4(0, 0, 0, 0);
    *(uint4*)(kbase + ((0 ^ (row & 3)) << 4)) = ((uint4*)kv16)[0];
    *(uint4*)(kbase + ((1 ^ (row & 3)) << 4)) = ((uint4*)kv16)[1];
    *(uint4*)(kbase + ((2 ^ (row & 3)) << 4)) = zz;
    *(uint4*)(kbase + ((3 ^ (row & 3)) << 4)) = zz;
#pragma unroll
    for (int d = 0; d < 16; ++d) vsh[d * 248 + row] = vv16[d];
  }
  __syncthreads();

  int lane = tid & 63, wid = tid >> 6;
  int g = lane >> 4, q15 = lane & 15;
  int wq0 = wid * 64;
  char* pw_base = (char*)psh + wid * 512;

  bf16x8 qf[4];
#pragma unroll
  for (int i = 0; i < 4; ++i) {
    int q = wq0 + i * 16 + q15;
    int qq = q < LTOK ? q : 0;
    int p = pbase + (qq / 15) * WIMG + (qq % 15);
    U16B u; u.u = make_uint4(0, 0, 0, 0);
    if (g < 2) u.u = *(const uint4*)(qc + ((size_t)b * PSTRIDE + p) * 128 + hh * 16 + g * 8);
    qf[i] = u.v;
  }

  float m_[4], ls[4];
  f32x4 oac[4] = {};
#pragma unroll
  for (int i = 0; i < 4; ++i) { m_[i] = -3.0e38f; ls[i] = 0.f; }
  const f32x4 zacc = {};

  for (int ck = 0; ck < 15; ++ck) {
    int rowb = ck * 16 + q15;
    bf16x8 kf = *(const bf16x8*)((const char*)ksh + rowb * 64 + ((g ^ (rowb & 3)) << 4));
    U16B vu; vu.u = make_uint4(0, 0, 0, 0);
    if (g < 2) vu.u = *(const uint4*)((const char*)vsh + (q15 * 248 + ck * 16 + g * 8) * 2);
    bf16x8 vf = vu.v;
#pragma unroll
    for (int i = 0; i < 4; ++i) {
      f32x4 st = __builtin_amdgcn_mfma_f32_16x16x32_bf16(kf, qf[i], zacc, 0, 0, 0);
      float s0 = st[0], s1 = st[1], s2 = st[2], s3 = st[3];
      if (ck == 14) {
        s0 = (g == 0) ? s0 : -3.0e38f;
        s1 = -3.0e38f; s2 = -3.0e38f; s3 = -3.0e38f;
      }
      float cm = fmaxf(fmaxf(s0, s1), fmaxf(s2, s3));
      cm = fmaxf(cm, __shfl_xor(cm, 16));
      cm = fmaxf(cm, __shfl_xor(cm, 32));
      float mn = fmaxf(m_[i], cm);
      float corr = __expf(m_[i] - mn);
      float p0 = __expf(s0 - mn), p1 = __expf(s1 - mn);
      float p2 = __expf(s2 - mn), p3 = __expf(s3 - mn);
      float ps = (p0 + p1) + (p2 + p3);
      ps += __shfl_xor(ps, 16);
      ps += __shfl_xor(ps, 32);
      ls[i] = ls[i] * corr + ps;
      m_[i] = mn;
      unsigned w0 = (unsigned)f2bf(p0) | ((unsigned)f2bf(p1) << 16);
      unsigned w1 = (unsigned)f2bf(p2) | ((unsigned)f2bf(p3) << 16);
      *(uint2*)(pw_base + q15 * 32 + g * 8) = make_uint2(w0, w1);
      U16B pu; pu.u = make_uint4(0, 0, 0, 0);
      if (g < 2) pu.u = *(const uint4*)(pw_base + q15 * 32 + g * 16);
      f32x4 oc = oac[i];
      oc[0] *= corr; oc[1] *= corr; oc[2] *= corr; oc[3] *= corr;
      oac[i] = __builtin_amdgcn_mfma_f32_16x16x32_bf16(vf, pu.v, oc, 0, 0, 0);
    }
  }

  __hip_bfloat16* cb = ctx + (size_t)b * PSTRIDE * 128 + hh * 16;
#pragma unroll
  for (int i = 0; i < 4; ++i) {
    float inv = 1.f / ls[i];
    int qo = wq0 + i * 16 + q15;
    if (qo < LTOK) {
      unsigned lo = (unsigned)f2bf(oac[i][0] * inv) | ((unsigned)f2bf(oac[i][1] * inv) << 16);
      unsigned hi = (unsigned)f2bf(oac[i][2] * inv) | ((unsigned)f2bf(oac[i][3] * inv) << 16);
      int p = pbase + (qo / 15) * WIMG + (qo % 15);
      *(uint2*)(cb + (size_t)p * 128 + g * 4) = make_uint2(lo, hi);
    }
  }
}

// ---------------------------------------------------------------------------
// 4) out-proj MFMA GEMM + bias + residual -> padded fb bf16 (unchanged)
// ---------------------------------------------------------------------------
__global__ void __launch_bounds__(256) k_outproj_mfma(
    const __hip_bfloat16* __restrict__ ctx, const __hip_bfloat16* __restrict__ wob,
    const float* __restrict__ opb, const __hip_bfloat16* __restrict__ lidb,
    __hip_bfloat16* __restrict__ fb) {
  int m0 = blockIdx.x * 128, b = blockIdx.z;
  int lane = threadIdx.x & 63, wid = threadIdx.x >> 6;
  int wm = (wid >> 1) * 64, wn = (wid & 1) * 64;
  const __hip_bfloat16* Ab = ctx + (size_t)b * PSTRIDE * 128;
  f32x4 acc[4][4] = {};
  for (int kc = 0; kc < 128; kc += 32) {
    bf16x8 af[4], bfr[4];
#pragma unroll
    for (int i = 0; i < 4; ++i)
      af[i] = ldfrag(Ab + (size_t)(m0 + wm + i * 16) * 128 + kc, 128, lane);
#pragma unroll
    for (int j = 0; j < 4; ++j)
      bfr[j] = ldfrag(wob + (size_t)(wn + j * 16) * 128 + kc, 128, lane);
#pragma unroll
    for (int i = 0; i < 4; ++i)
#pragma unroll
      for (int j = 0; j < 4; ++j)
        acc[i][j] = __builtin_amdgcn_mfma_f32_16x16x32_bf16(af[i], bfr[j], acc[i][j], 0, 0, 0);
  }
  int col = lane & 15, rq = lane >> 4;
  const __hip_bfloat16* lb = lidb + (size_t)b * PSTRIDE * 128;
  __hip_bfloat16* fbp = fb + (size_t)b * FBSZ;
#pragma unroll
  for (int j = 0; j < 4; ++j) {
    int n = wn + j * 16 + col;
    float bs = opb[n];
#pragma unroll
    for (int i = 0; i < 4; ++i) {
#pragma unroll
      for (int r = 0; r < 4; ++r) {
        int m = m0 + wm + i * 16 + rq * 4 + r;
        if (m < HW) {
          float v = acc[i][j][r] + bs + __bfloat162float(lb[(size_t)m * 128 + n]);
          int hhh = m / WIMG, www = m % WIMG;
          fbp[((size_t)(hhh + 1) * FBROW + (www + 1)) * 128 + n] = __float2bfloat16(v);
        }
      }
    }
  }
}

// ---------------------------------------------------------------------------
// 5) 3x3 conv 128->256 + BN + ReLU, implicit GEMM.
//    A halo LDS-staged once; B frag-major direct-to-register, 3-deep rotating
//    prefetch, barrier-free main loop (compiler counted-vmcnt pipelining).
// ---------------------------------------------------------------------------
__global__ void __launch_bounds__(256) k_conv_mfma(
    const __hip_bfloat16* __restrict__ fb, const __hip_bfloat16* __restrict__ wcb,
    const float* __restrict__ g, const float* __restrict__ be,
    const float* __restrict__ mu, const float* __restrict__ var,
    float* __restrict__ out) {
  __shared__ __align__(16) uint4 Asm[2976];      // A halo: [dy*16+kgrp][px 0..61]
  int bx = blockIdx.x;                 // 0..1079: h*6 + strip*2 + ocg
  int h = bx / 6, rem = bx % 6;
  int strip = rem >> 1, ocg = rem & 1;
  int w0 = strip * 60;
  int b = blockIdx.z;
  int tid = threadIdx.x, lane = tid & 63, wid = tid >> 6;
  int q15 = lane & 15, kg = lane >> 4;
  int wpx = (wid & 1) * 32;            // pixel half
  const __hip_bfloat16* fbb = fb + (size_t)b * FBSZ;
  // frag-major B base for this wave: oc16 blocks (ocg*8 + (wid>>1)*4 + j)
  const __hip_bfloat16* Bw = wcb + (size_t)(ocg * 8 + (wid >> 1) * 4) * 18432 + lane * 8;

  // ---- stage A halo (3 rows x 62 px, K-major) ----
#pragma unroll
  for (int it = 0; it < 12; ++it) {
    int slot = it * 256 + tid;
    if (slot < 2976) {
      int px = slot % 62;
      int rowk = slot / 62;            // dy*16 + kgrp
      int dy = rowk >> 4, kgrp = rowk & 15;
      Asm[slot] = *(const uint4*)(fbb + ((size_t)(h + dy) * FBROW + (w0 + px)) * 128 + kgrp * 8);
    }
  }

#define LOADB(dst, t)                                                          \
  {                                                                            \
    int tap_ = (t) >> 2, ch_ = (t) & 3;                                        \
    _Pragma("unroll") for (int j = 0; j < 4; ++j)                              \
        dst[j] = *(const bf16x8*)(Bw + (size_t)j * 18432 + tap_ * 2048 + ch_ * 512); \
  }

  bf16x8 bp0[4], bp1[4], bp2[4];
  LOADB(bp0, 0);
  LOADB(bp1, 1);
  LOADB(bp2, 2);
  __syncthreads();                     // A halo ready (single barrier)

  f32x4 acc[2][4] = {};

#define STEP(t, bp)                                                            \
  {                                                                            \
    int tap_ = (t) >> 2, ch_ = (t) & 3;                                        \
    int dy_ = tap_ / 3, dx_ = tap_ % 3;                                        \
    int rowk_ = (dy_ * 16 + ch_ * 4 + kg) * 62;                                \
    bf16x8 af[2];                                                              \
    _Pragma("unroll") for (int i = 0; i < 2; ++i)                              \
        af[i] = *(const bf16x8*)&Asm[rowk_ + wpx + i * 16 + q15 + dx_];        \
    _Pragma("unroll") for (int i = 0; i < 2; ++i)                              \
        _Pragma("unroll") for (int j = 0; j < 4; ++j)                          \
            acc[i][j] = __builtin_amdgcn_mfma_f32_16x16x32_bf16(af[i], bp[j], acc[i][j], 0, 0, 0); \
  }

#pragma unroll
  for (int t = 0; t < 36; t += 3) {
    STEP(t, bp0);
    if (t + 3 < 36) LOADB(bp0, t + 3);
    STEP(t + 1, bp1);
    if (t + 4 < 36) LOADB(bp1, t + 4);
    STEP(t + 2, bp2);
    if (t + 5 < 36) LOADB(bp2, t + 5);
  }
#undef STEP
#undef LOADB

  // ---- epilogue: BN + ReLU + store (D: col=oc (q15), row=px (kg*4+r)) ----
  int ocbase = ocg * 128 + (wid >> 1) * 64;
#pragma unroll
  for (int j = 0; j < 4; ++j) {
    int oc = ocbase + j * 16 + q15;
    float s = g[oc] * rsqrtf(var[oc] + 1e-5f);
    float mm = mu[oc], bb = be[oc];
#pragma unroll
    for (int i = 0; i < 2; ++i) {
      int pxb = wpx + i * 16 + kg * 4;
      if (pxb < 60) {
        float4 o4;
        o4.x = fmaxf((acc[i][j][0] - mm) * s + bb, 0.f);
        o4.y = fmaxf((acc[i][j][1] - mm) * s + bb, 0.f);
        o4.z = fmaxf((acc[i][j][2] - mm) * s + bb, 0.f);
        o4.w = fmaxf((acc[i][j][3] - mm) * s + bb, 0.f);
        *(float4*)(&out[(size_t)(b * 256 + oc) * HW + h * WIMG + w0 + pxb]) = o4;
      }
    }
  }
}

// ---------------------------------------------------------------------------
extern "C" void kernel_launch(void* const* d_in, const int* in_sizes, int n_in,
                              void* d_out, int out_size, void* d_ws, size_t ws_size,
                              hipStream_t stream) {
  const float* camera = (const float*)d_in[0];
  const float* lidar  = (const float*)d_in[1];
  const float* cam_w  = (const float*)d_in[2];
  const float* cam_g  = (const float*)d_in[3];
  const float* cam_b  = (const float*)d_in[4];
  const float* cam_m  = (const float*)d_in[5];
  const float* cam_v  = (const float*)d_in[6];
  const float* lid_w  = (const float*)d_in[7];
  const float* lid_g  = (const float*)d_in[8];
  const float* lid_b  = (const float*)d_in[9];
  const float* lid_m  = (const float*)d_in[10];
  const float* lid_v  = (const float*)d_in[11];
  const float* ipw    = (const float*)d_in[12];
  const float* ipb    = (const float*)d_in[13];
  const float* opw    = (const float*)d_in[14];
  const float* opb    = (const float*)d_in[15];
  const float* ocw    = (const float*)d_in[16];
  const float* ocg    = (const float*)d_in[17];
  const float* ocb    = (const float*)d_in[18];
  const float* ocm    = (const float*)d_in[19];
  const float* ocv    = (const float*)d_in[20];

  __hip_bfloat16* ws = (__hip_bfloat16*)d_ws;
  const size_t NP = (size_t)2 * PSTRIDE * 128;
  __hip_bfloat16* cam_bf = ws;                    // aliased by fb later
  __hip_bfloat16* lid_bf = ws + NP;
  __hip_bfloat16* qc     = ws + 2 * NP;           // q, then ctx (in-place)
  __hip_bfloat16* kvb    = ws + 3 * NP;           // [p][256], 2*NP elements
  __hip_bfloat16* wipb   = ws + 5 * NP;           // 384*128
  __hip_bfloat16* wob    = wipb + 384 * 128;      // 128*128
  __hip_bfloat16* wcb    = wob + 128 * 128;       // 256*9*128 (frag-major)
  __hip_bfloat16* wcamb  = wcb + 256 * 9 * 128;   // 128*128 (Kpad=128)
  __hip_bfloat16* wlidb  = wcamb + 128 * 128;     // 128*256
  __hip_bfloat16* fbbuf  = cam_bf;

  dim3 blk(256);
  // weight prep
  hipLaunchKernelGGL(k_cast, dim3(192), blk, 0, stream, ipw, wipb, 384 * 128);
  hipLaunchKernelGGL(k_cast, dim3(64), blk, 0, stream, opw, wob, 128 * 128);
  hipLaunchKernelGGL(k_prepw2, dim3(1152), blk, 0, stream, ocw, wcb);
  hipLaunchKernelGGL(k_prepproj, dim3(64), blk, 0, stream, cam_w, wcamb, 80, 128);
  hipLaunchKernelGGL(k_prepproj, dim3(128), blk, 0, stream, lid_w, wlidb, 256, 256);
  // projections -> pixel-major bf16 (MFMA implicit GEMM)
  dim3 gproj(254, 1, 2);
  hipLaunchKernelGGL(k_proj_mfma, gproj, blk, 0, stream,
                     camera, wcamb, cam_g, cam_b, cam_m, cam_v, cam_bf, 80, 128);
  hipLaunchKernelGGL(k_proj_mfma, gproj, blk, 0, stream,
                     lidar, wlidb, lid_g, lid_b, lid_m, lid_v, lid_bf, 256, 256);
  // qkv GEMMs
  hipLaunchKernelGGL(k_gemm_bias, dim3(254, 1, 2), blk, 0, stream,
                     lid_bf, wipb, ipb, qc, 128, 128);
  hipLaunchKernelGGL(k_gemm_bias, dim3(254, 2, 2), blk, 0, stream,
                     cam_bf, wipb + 128 * 128, ipb + 128, kvb, 128, 256);
  // attention (qc -> qc in place)
  hipLaunchKernelGGL(k_attn_mfma, dim3(288, 8), blk, 0, stream, qc, kvb, qc);
  // zero padded fb (aliases cam_bf, dead after kv gemm)
  int n16 = (int)((2 * FBSZ * 2) / 16);
  hipLaunchKernelGGL(k_zero, dim3((n16 + 255) / 256), blk, 0, stream, (uint4*)fbbuf, n16);
  // out-proj + residual -> fb
  hipLaunchKernelGGL(k_outproj_mfma, dim3(254, 1, 2), blk, 0, stream,
                     qc, wob, opb, lid_bf, fbbuf);
  // conv + BN + ReLU
  hipLaunchKernelGGL(k_conv_mfma, dim3(1080, 1, 2), blk, 0, stream,
                     fbbuf, wcb, ocg, ocb, ocm, ocv, (float*)d_out);
}